// Round 2
// baseline (2840.567 us; speedup 1.0000x reference)
//
#include <hip/hip_runtime.h>
#include <cstddef>

#define C_ 256
#define H_ 128
#define W_ 128
#define HW_ 16384
#define NH_ 8
#define NWIN_ 256   // windows per batch image (16x16)
#define EPS_ 1e-5f

// ---------------------------------------------------------------------------
// K1 (per batch): qkv 1x1 conv as GEMM; epilogue scatters to window layout
//     qkv_s[qkvi][win][head][pos][d]  (win = hh*16+ww, pos = ws1*8+ws2, d<32)
// ---------------------------------------------------------------------------
__global__ __launch_bounds__(256) void k1_qkv_gemm(
    const float* __restrict__ xb, const float* __restrict__ wq,
    const float* __restrict__ bias, float* __restrict__ qkv_s) {
  __shared__ float s_w[16][64];
  __shared__ float s_x[16][64];
  const int tid = threadIdx.x;
  const int tx = tid & 15, ty = tid >> 4;
  const int p0 = blockIdx.x * 64;
  const int oc0 = blockIdx.y * 64;

  float acc[4][4];
#pragma unroll
  for (int i = 0; i < 4; ++i)
#pragma unroll
    for (int j = 0; j < 4; ++j) acc[i][j] = 0.f;

  for (int k0 = 0; k0 < 256; k0 += 16) {
    {
      const int m = tid >> 2;
      const int kg = (tid & 3) * 4;
      const float4 w4 = *reinterpret_cast<const float4*>(
          &wq[(size_t)(oc0 + m) * 256 + k0 + kg]);
      s_w[kg + 0][m] = w4.x;
      s_w[kg + 1][m] = w4.y;
      s_w[kg + 2][m] = w4.z;
      s_w[kg + 3][m] = w4.w;
    }
    {
      const int kk = tid >> 4;
      const int cg = (tid & 15) * 4;
      *reinterpret_cast<float4*>(&s_x[kk][cg]) =
          *reinterpret_cast<const float4*>(&xb[(size_t)(k0 + kk) * HW_ + p0 + cg]);
    }
    __syncthreads();
#pragma unroll
    for (int kk = 0; kk < 16; ++kk) {
      const float4 a = *reinterpret_cast<const float4*>(&s_w[kk][ty * 4]);
      const float4 bv = *reinterpret_cast<const float4*>(&s_x[kk][tx * 4]);
      acc[0][0] = fmaf(a.x, bv.x, acc[0][0]);
      acc[0][1] = fmaf(a.x, bv.y, acc[0][1]);
      acc[0][2] = fmaf(a.x, bv.z, acc[0][2]);
      acc[0][3] = fmaf(a.x, bv.w, acc[0][3]);
      acc[1][0] = fmaf(a.y, bv.x, acc[1][0]);
      acc[1][1] = fmaf(a.y, bv.y, acc[1][1]);
      acc[1][2] = fmaf(a.y, bv.z, acc[1][2]);
      acc[1][3] = fmaf(a.y, bv.w, acc[1][3]);
      acc[2][0] = fmaf(a.z, bv.x, acc[2][0]);
      acc[2][1] = fmaf(a.z, bv.y, acc[2][1]);
      acc[2][2] = fmaf(a.z, bv.z, acc[2][2]);
      acc[2][3] = fmaf(a.z, bv.w, acc[2][3]);
      acc[3][0] = fmaf(a.w, bv.x, acc[3][0]);
      acc[3][1] = fmaf(a.w, bv.y, acc[3][1]);
      acc[3][2] = fmaf(a.w, bv.z, acc[3][2]);
      acc[3][3] = fmaf(a.w, bv.w, acc[3][3]);
    }
    __syncthreads();
  }

  const int y = p0 >> 7;          // image row (all 64 px share it)
  const int xcol0 = p0 & 127;
  const int hh = y >> 3, ws1 = y & 7;
  const int oc = oc0 + ty * 4;
  const int qkvi = oc >> 8;
  const int hhead = (oc >> 5) & 7;
  const int d0 = oc & 31;
  const float b0 = bias[oc + 0], b1 = bias[oc + 1], b2 = bias[oc + 2], b3 = bias[oc + 3];
#pragma unroll
  for (int j = 0; j < 4; ++j) {
    const int px = xcol0 + tx * 4 + j;
    const int ww = px >> 3, ws2 = px & 7;
    const int win = hh * 16 + ww;
    const size_t addr =
        ((((size_t)qkvi * NWIN_ + win) * NH_ + hhead) * 64 + (ws1 * 8 + ws2)) * 32 + d0;
    float4 v;
    v.x = acc[0][j] + b0;
    v.y = acc[1][j] + b1;
    v.z = acc[2][j] + b2;
    v.w = acc[3][j] + b3;
    *reinterpret_cast<float4*>(&qkv_s[addr]) = v;
  }
}

// ---------------------------------------------------------------------------
// K2 (per batch): grouped 3x3 conv (groups=8) + bias + BN(eval) + ReLU
// ---------------------------------------------------------------------------
__global__ __launch_bounds__(256) void k2_local(
    const float* __restrict__ xb, const float* __restrict__ lw,
    const float* __restrict__ lb, const float* __restrict__ bng,
    const float* __restrict__ bnb, float* __restrict__ local_s) {
  __shared__ float xt[18 * 35];
  __shared__ float wl[288];
  const int tid = threadIdx.x;
  const int g = blockIdx.y;
  const int ty0 = (blockIdx.x >> 2) * 16;
  const int tx0 = (blockIdx.x & 3) * 32;
  const int py = tid >> 4;
  const int px = (tid & 15) * 2;

  float acc0[32], acc1[32];
#pragma unroll
  for (int oc = 0; oc < 32; ++oc) { acc0[oc] = 0.f; acc1[oc] = 0.f; }

  for (int ic = 0; ic < 32; ++ic) {
    __syncthreads();
    const float* xp = xb + (size_t)(g * 32 + ic) * HW_;
    for (int i = tid; i < 18 * 34; i += 256) {
      const int r = i / 34, cc = i % 34;
      const int gy = ty0 + r - 1, gx = tx0 + cc - 1;
      float v = 0.f;
      if (gy >= 0 && gy < H_ && gx >= 0 && gx < W_) v = xp[gy * W_ + gx];
      xt[r * 35 + cc] = v;
    }
    for (int i = tid; i < 288; i += 256) {   // FIXED: was `if (tid < 288)` w/ 256 thr
      const int oc = i / 9, k = i % 9;
      wl[i] = lw[((size_t)(g * 32 + oc) * 32 + ic) * 9 + k];
    }
    __syncthreads();
    float nb[3][4];
#pragma unroll
    for (int dy = 0; dy < 3; ++dy)
#pragma unroll
      for (int dx = 0; dx < 4; ++dx) nb[dy][dx] = xt[(py + dy) * 35 + px + dx];
#pragma unroll
    for (int oc = 0; oc < 32; ++oc) {
      const float* wp = &wl[oc * 9];
      float s0 = 0.f, s1 = 0.f;
#pragma unroll
      for (int dy = 0; dy < 3; ++dy)
#pragma unroll
        for (int dx = 0; dx < 3; ++dx) {
          const float wv = wp[dy * 3 + dx];
          s0 = fmaf(nb[dy][dx], wv, s0);
          s1 = fmaf(nb[dy][dx + 1], wv, s1);
        }
      acc0[oc] += s0;
      acc1[oc] += s1;
    }
  }

  const int gy = ty0 + py;
#pragma unroll
  for (int oc = 0; oc < 32; ++oc) {
    const int c = g * 32 + oc;
    const float scale = bng[c] / sqrtf(1.0f + EPS_);
    const float cb = lb[c], sb = bnb[c];
    const float v0 = fmaxf(fmaf(acc0[oc] + cb, scale, sb), 0.f);
    const float v1 = fmaxf(fmaf(acc1[oc] + cb, scale, sb), 0.f);
    *reinterpret_cast<float2*>(&local_s[(size_t)c * HW_ + gy * W_ + tx0 + px]) =
        make_float2(v0, v1);
  }
}

// ---------------------------------------------------------------------------
// K3 (per batch): window attention. 1 wave = 1 (window, head). lane = query.
//     2 waves / block -> 39 KB LDS (safe under any per-WG limit)
// ---------------------------------------------------------------------------
__global__ __launch_bounds__(128) void k3_attn(
    const float* __restrict__ qkv_s, const float* __restrict__ rpb,
    float* __restrict__ attn_s) {
  __shared__ float kvs[2][2][64 * 32];
  __shared__ float rpb_s[225 * 8];
  const int tid = threadIdx.x;
  const int wid = tid >> 6, lane = tid & 63;
  const int pid = blockIdx.x * 2 + wid;
  const int win = pid >> 3, h = pid & 7;
  const int hh = win >> 4, ww = win & 15;

  for (int i = tid; i < 225 * 8; i += 128) rpb_s[i] = rpb[i];

  const size_t qbase = (((size_t)0 * NWIN_ + win) * NH_ + h) * 2048;
  const size_t kbase = (((size_t)1 * NWIN_ + win) * NH_ + h) * 2048;
  const size_t vbase = (((size_t)2 * NWIN_ + win) * NH_ + h) * 2048;

  float* Kl = kvs[wid][0];
  float* Vl = kvs[wid][1];
#pragma unroll
  for (int r = 0; r < 8; ++r) {
    const int e = r * 256 + lane * 4;
    *reinterpret_cast<float4*>(&Kl[e]) =
        *reinterpret_cast<const float4*>(&qkv_s[kbase + e]);
    *reinterpret_cast<float4*>(&Vl[e]) =
        *reinterpret_cast<const float4*>(&qkv_s[vbase + e]);
  }
  float4 qreg[8];
#pragma unroll
  for (int dd = 0; dd < 8; ++dd)
    qreg[dd] = *reinterpret_cast<const float4*>(&qkv_s[qbase + lane * 32 + dd * 4]);

  __syncthreads();

  float s[64];
#pragma unroll
  for (int j = 0; j < 64; ++j) {
    const float* kr = &Kl[j * 32];
    float sj = 0.f;
#pragma unroll
    for (int dd = 0; dd < 8; ++dd) {
      const float4 kv = *reinterpret_cast<const float4*>(&kr[dd * 4]);
      sj = fmaf(qreg[dd].x, kv.x, sj);
      sj = fmaf(qreg[dd].y, kv.y, sj);
      sj = fmaf(qreg[dd].z, kv.z, sj);
      sj = fmaf(qreg[dd].w, kv.w, sj);
    }
    s[j] = sj;
  }

  const float scale = 0.17677669529663687f;  // 32^-0.5
  const int r1 = lane >> 3, c1 = lane & 7;
  float m = -1e30f;
#pragma unroll
  for (int j = 0; j < 64; ++j) {
    const int jr = j >> 3, jc = j & 7;
    const int idx = (r1 - jr + 7) * 15 + (c1 - jc + 7);
    s[j] = fmaf(s[j], scale, rpb_s[idx * 8 + h]);
    m = fmaxf(m, s[j]);
  }
  float sum = 0.f;
#pragma unroll
  for (int j = 0; j < 64; ++j) {
    s[j] = __expf(s[j] - m);
    sum += s[j];
  }
  const float inv = 1.0f / sum;

  float o[32];
#pragma unroll
  for (int d = 0; d < 32; ++d) o[d] = 0.f;
#pragma unroll
  for (int j = 0; j < 64; ++j) {
    const float pj = s[j] * inv;
    const float* vr = &Vl[j * 32];
#pragma unroll
    for (int dd = 0; dd < 8; ++dd) {
      const float4 vv = *reinterpret_cast<const float4*>(&vr[dd * 4]);
      o[dd * 4 + 0] = fmaf(pj, vv.x, o[dd * 4 + 0]);
      o[dd * 4 + 1] = fmaf(pj, vv.y, o[dd * 4 + 1]);
      o[dd * 4 + 2] = fmaf(pj, vv.z, o[dd * 4 + 2]);
      o[dd * 4 + 3] = fmaf(pj, vv.w, o[dd * 4 + 3]);
    }
  }

  const int yy = hh * 8 + r1, xx = ww * 8 + c1;
  const size_t obase = ((size_t)(h * 32) * H_ + yy) * W_ + xx;
#pragma unroll
  for (int d = 0; d < 32; ++d) attn_s[obase + (size_t)d * HW_] = o[d];
}

// ---------------------------------------------------------------------------
// K4 (per batch): ax (8x1 pool, reflect-bottom) + ay (1x8, reflect-right)
//                 + local; writes pool IN-PLACE over local_s (same-idx RMW)
// ---------------------------------------------------------------------------
__global__ __launch_bounds__(256) void k4_pool(
    const float* __restrict__ attn_s, float* __restrict__ localpool) {
  const int bid = blockIdx.x;
  const int c = bid >> 6;
  const int rp = bid & 63;
  const int i = rp * 2 + (threadIdx.x >> 7);
  const int j = threadIdx.x & 127;
  const float* ap = attn_s + (size_t)c * HW_;
  float sx = 0.f;
#pragma unroll
  for (int dr = -3; dr <= 4; ++dr) {
    int r = i + dr;
    if (r < 0 || r > 128) continue;
    if (r == 128) r = 126;
    sx += ap[r * W_ + j];
  }
  float sy = 0.f;
#pragma unroll
  for (int dc = -3; dc <= 4; ++dc) {
    int cc = j + dc;
    if (cc < 0 || cc > 128) continue;
    if (cc == 128) cc = 126;
    sy += ap[i * W_ + cc];
  }
  const size_t idx = (size_t)c * HW_ + i * W_ + j;
  localpool[idx] = (sx + sy) * 0.125f + localpool[idx];
}

// ---------------------------------------------------------------------------
// K5 (per batch): depthwise 3x3 on reflect(0,1,0,1)-padded pool + bias + BN
//                 writes over attn_s (attn dead after K4)
// ---------------------------------------------------------------------------
__global__ __launch_bounds__(256) void k5_dw(
    const float* __restrict__ pool, const float* __restrict__ dww,
    const float* __restrict__ dwb, const float* __restrict__ bng,
    const float* __restrict__ bnb, float* __restrict__ dwout) {
  const int bid = blockIdx.x;
  const int c = bid >> 6;
  const int rp = bid & 63;
  const int i = rp * 2 + (threadIdx.x >> 7);
  const int j = threadIdx.x & 127;
  const float* pp = pool + (size_t)c * HW_;
  const float* wp = dww + c * 9;
  float acc = 0.f;
#pragma unroll
  for (int dy = 0; dy < 3; ++dy) {
    int r = i + dy - 1;
    if (r < 0) continue;
    if (r == 128) r = 126;
#pragma unroll
    for (int dx = 0; dx < 3; ++dx) {
      int cc = j + dx - 1;
      if (cc < 0) continue;
      if (cc == 128) cc = 126;
      acc = fmaf(wp[dy * 3 + dx], pp[r * W_ + cc], acc);
    }
  }
  const float scale = bng[c] / sqrtf(1.0f + EPS_);
  dwout[(size_t)c * HW_ + i * W_ + j] = fmaf(acc + dwb[c], scale, bnb[c]);
}

// ---------------------------------------------------------------------------
// K6 (per batch): pointwise 1x1 conv GEMM -> d_out slice
// ---------------------------------------------------------------------------
__global__ __launch_bounds__(256) void k6_pw_gemm(
    const float* __restrict__ xin, const float* __restrict__ wp,
    const float* __restrict__ bias, float* __restrict__ outb) {
  __shared__ float s_w[16][64];
  __shared__ float s_x[16][64];
  const int tid = threadIdx.x;
  const int tx = tid & 15, ty = tid >> 4;
  const int p0 = blockIdx.x * 64;
  const int oc0 = blockIdx.y * 64;

  float acc[4][4];
#pragma unroll
  for (int i = 0; i < 4; ++i)
#pragma unroll
    for (int j = 0; j < 4; ++j) acc[i][j] = 0.f;

  for (int k0 = 0; k0 < 256; k0 += 16) {
    {
      const int m = tid >> 2;
      const int kg = (tid & 3) * 4;
      const float4 w4 = *reinterpret_cast<const float4*>(
          &wp[(size_t)(oc0 + m) * 256 + k0 + kg]);
      s_w[kg + 0][m] = w4.x;
      s_w[kg + 1][m] = w4.y;
      s_w[kg + 2][m] = w4.z;
      s_w[kg + 3][m] = w4.w;
    }
    {
      const int kk = tid >> 4;
      const int cg = (tid & 15) * 4;
      *reinterpret_cast<float4*>(&s_x[kk][cg]) =
          *reinterpret_cast<const float4*>(&xin[(size_t)(k0 + kk) * HW_ + p0 + cg]);
    }
    __syncthreads();
#pragma unroll
    for (int kk = 0; kk < 16; ++kk) {
      const float4 a = *reinterpret_cast<const float4*>(&s_w[kk][ty * 4]);
      const float4 bv = *reinterpret_cast<const float4*>(&s_x[kk][tx * 4]);
      acc[0][0] = fmaf(a.x, bv.x, acc[0][0]);
      acc[0][1] = fmaf(a.x, bv.y, acc[0][1]);
      acc[0][2] = fmaf(a.x, bv.z, acc[0][2]);
      acc[0][3] = fmaf(a.x, bv.w, acc[0][3]);
      acc[1][0] = fmaf(a.y, bv.x, acc[1][0]);
      acc[1][1] = fmaf(a.y, bv.y, acc[1][1]);
      acc[1][2] = fmaf(a.y, bv.z, acc[1][2]);
      acc[1][3] = fmaf(a.y, bv.w, acc[1][3]);
      acc[2][0] = fmaf(a.z, bv.x, acc[2][0]);
      acc[2][1] = fmaf(a.z, bv.y, acc[2][1]);
      acc[2][2] = fmaf(a.z, bv.z, acc[2][2]);
      acc[2][3] = fmaf(a.z, bv.w, acc[2][3]);
      acc[3][0] = fmaf(a.w, bv.x, acc[3][0]);
      acc[3][1] = fmaf(a.w, bv.y, acc[3][1]);
      acc[3][2] = fmaf(a.w, bv.z, acc[3][2]);
      acc[3][3] = fmaf(a.w, bv.w, acc[3][3]);
    }
    __syncthreads();
  }

#pragma unroll
  for (int i = 0; i < 4; ++i) {
    const int oc = oc0 + ty * 4 + i;
    const float bo = bias[oc];
    float4 v;
    v.x = acc[i][0] + bo;
    v.y = acc[i][1] + bo;
    v.z = acc[i][2] + bo;
    v.w = acc[i][3] + bo;
    *reinterpret_cast<float4*>(&outb[(size_t)oc * HW_ + p0 + tx * 4]) = v;
  }
}

// ---------------------------------------------------------------------------
extern "C" void kernel_launch(void* const* d_in, const int* in_sizes, int n_in,
                              void* d_out, int out_size, void* d_ws, size_t ws_size,
                              hipStream_t stream) {
  const float* x          = (const float*)d_in[0];
  const float* qkv_w      = (const float*)d_in[1];
  const float* qkv_b      = (const float*)d_in[2];
  const float* local_w    = (const float*)d_in[3];
  const float* local_b    = (const float*)d_in[4];
  const float* local_bn_g = (const float*)d_in[5];
  const float* local_bn_b = (const float*)d_in[6];
  const float* rpb        = (const float*)d_in[7];
  const float* proj_dw_w  = (const float*)d_in[8];
  const float* proj_dw_b  = (const float*)d_in[9];
  const float* proj_bn_g  = (const float*)d_in[10];
  const float* proj_bn_b  = (const float*)d_in[11];
  const float* proj_pw_w  = (const float*)d_in[12];
  const float* proj_pw_b  = (const float*)d_in[13];
  float* out = (float*)d_out;
  float* ws = (float*)d_ws;

  const size_t CHW = (size_t)C_ * HW_;          // 4,194,304 floats / image
  const size_t QKV_S = 3 * CHW;                 // 12.6M floats (one batch)
  const size_t NEED_BYTES = (QKV_S + 2 * CHW) * sizeof(float);  // 80 MB
  if (ws_size < NEED_BYTES) return;  // diagnosable fail instead of mem-fault

  float* qkv_s  = ws;                 // per-batch qkv (window layout)
  float* attn_s = ws + QKV_S;         // attn out -> later dw out
  float* local_s = attn_s + CHW;      // local out -> later pool out (in-place)

  for (int bb = 0; bb < 8; ++bb) {
    const float* xb = x + (size_t)bb * CHW;
    float* outb = out + (size_t)bb * CHW;
    k1_qkv_gemm<<<dim3(256, 12), 256, 0, stream>>>(xb, qkv_w, qkv_b, qkv_s);
    k2_local<<<dim3(32, NH_), 256, 0, stream>>>(xb, local_w, local_b,
                                                local_bn_g, local_bn_b, local_s);
    k3_attn<<<dim3(1024), 128, 0, stream>>>(qkv_s, rpb, attn_s);
    k4_pool<<<dim3(C_ * 64), 256, 0, stream>>>(attn_s, local_s);
    k5_dw<<<dim3(C_ * 64), 256, 0, stream>>>(local_s, proj_dw_w, proj_dw_b,
                                             proj_bn_g, proj_bn_b, attn_s);
    k6_pw_gemm<<<dim3(256, 4), 256, 0, stream>>>(attn_s, proj_pw_w, proj_pw_b, outb);
  }
}

// Round 6
// 2137.551 us; speedup vs baseline: 1.3289x; 1.3289x over previous
//
#include <hip/hip_runtime.h>
#include <cstddef>

#define C_ 256
#define H_ 128
#define W_ 128
#define HW_ 16384
#define NH_ 8
#define NWIN_ 256   // windows per batch image (16x16)
#define EPS_ 1e-5f

typedef short s16x8 __attribute__((ext_vector_type(8)));
typedef float f32x4 __attribute__((ext_vector_type(4)));

// RNE fp32 -> bf16(hi) + bf16(lo residual). f finite.
__device__ inline void bf16_split(float f, short& h, short& l) {
  unsigned u = __float_as_uint(f);
  unsigned hb = (u + 0x7FFFu + ((u >> 16) & 1u)) >> 16;
  float hf = __uint_as_float(hb << 16);
  h = (short)hb;
  float r = f - hf;                       // exact (Sterbenz)
  unsigned v = __float_as_uint(r);
  unsigned lb = (v + 0x7FFFu + ((v >> 16) & 1u)) >> 16;
  l = (short)lb;
}

// ---------------------------------------------------------------------------
// K1 (per batch): qkv 1x1 conv as split-bf16 MFMA GEMM.
//   C[oc][p] = sum_k W[oc][k] X[k][p], M=768, N=16384, K=256.
//   Tile 128(oc) x 128(p); blockIdx.x = image row y (N-tile = one row),
//   blockIdx.y = oc-tile. 4 waves as 2x2, each 64x64 (4x4 frags 16x16).
//   Split: W=Wh+Wl, X=Xh+Xl; acc += WhXh + WhXl + WlXh  (fp32-class accuracy).
//   LDS tiles [128][40] bf16: 80B row stride -> 16B-aligned b128 frag reads,
//   20-word stride tiles all 32 banks (balanced, conflict-free).
//   Epilogue scatters to window layout qkv_s[qkvi][win][head][pos][d].
// ---------------------------------------------------------------------------
__global__ __launch_bounds__(256) void k1_qkv_mfma(
    const float* __restrict__ xb, const float* __restrict__ wq,
    const float* __restrict__ bias, float* __restrict__ qkv_s) {
  __shared__ short s_a[2][128][40];   // [hi/lo][oc][k]
  __shared__ short s_b[2][128][40];   // [hi/lo][p][k]  (X transposed)
  const int tid = threadIdx.x;
  const int y   = blockIdx.x;          // image row; p0 = y*128
  const int oc0 = blockIdx.y * 128;

  const int lane = tid & 63;
  const int wid  = tid >> 6;
  const int m0w = (wid >> 1) * 64;     // wave row offset (oc)
  const int n0w = (wid & 1) * 64;      // wave col offset (p/x)

  f32x4 acc[4][4];
#pragma unroll
  for (int i = 0; i < 4; ++i)
#pragma unroll
    for (int j = 0; j < 4; ++j) acc[i][j] = f32x4{0.f, 0.f, 0.f, 0.f};

  const int pcol = tid & 127;          // p index for B staging
  const int kq0  = tid >> 7;           // 0..1

  for (int k0 = 0; k0 < 256; k0 += 32) {
    // --- stage A: W[oc0..+127][k0..+31] -> s_a (hi/lo) ---
#pragma unroll
    for (int i = 0; i < 4; ++i) {
      const int ff = tid + i * 256;    // float4 index, coalesced per wave
      const int row = ff >> 3;         // 0..127
      const int c4 = ff & 7;           // float4 within 32-k row
      const float4 w4 = *reinterpret_cast<const float4*>(
          &wq[(size_t)(oc0 + row) * 256 + k0 + c4 * 4]);
      short h0, h1, h2, h3, l0, l1, l2, l3;
      bf16_split(w4.x, h0, l0);
      bf16_split(w4.y, h1, l1);
      bf16_split(w4.z, h2, l2);
      bf16_split(w4.w, h3, l3);
      *reinterpret_cast<short4*>(&s_a[0][row][c4 * 4]) = make_short4(h0, h1, h2, h3);
      *reinterpret_cast<short4*>(&s_a[1][row][c4 * 4]) = make_short4(l0, l1, l2, l3);
    }
    // --- stage B: X[k0..+31][y*128 + 0..127] -> s_b transposed (hi/lo) ---
#pragma unroll
    for (int it = 0; it < 4; ++it) {
      const int kq = kq0 * 4 + it;     // 0..7
      short h[4], l[4];
#pragma unroll
      for (int e = 0; e < 4; ++e) {
        const float v = xb[(size_t)(k0 + kq * 4 + e) * HW_ + y * W_ + pcol];
        bf16_split(v, h[e], l[e]);
      }
      *reinterpret_cast<short4*>(&s_b[0][pcol][kq * 4]) = make_short4(h[0], h[1], h[2], h[3]);
      *reinterpret_cast<short4*>(&s_b[1][pcol][kq * 4]) = make_short4(l[0], l[1], l[2], l[3]);
    }
    __syncthreads();

    // --- fragments + MFMA ---
    const int mr = lane & 15;
    const int kg = (lane >> 4) * 8;    // blocked k: frag[j] = elem k = kg+j
    s16x8 ah[4], al[4], bh[4], bl[4];
#pragma unroll
    for (int fm = 0; fm < 4; ++fm) {
      ah[fm] = *reinterpret_cast<const s16x8*>(&s_a[0][m0w + fm * 16 + mr][kg]);
      al[fm] = *reinterpret_cast<const s16x8*>(&s_a[1][m0w + fm * 16 + mr][kg]);
    }
#pragma unroll
    for (int fn = 0; fn < 4; ++fn) {
      bh[fn] = *reinterpret_cast<const s16x8*>(&s_b[0][n0w + fn * 16 + mr][kg]);
      bl[fn] = *reinterpret_cast<const s16x8*>(&s_b[1][n0w + fn * 16 + mr][kg]);
    }
#pragma unroll
    for (int fm = 0; fm < 4; ++fm)
#pragma unroll
      for (int fn = 0; fn < 4; ++fn) {
        acc[fm][fn] = __builtin_amdgcn_mfma_f32_16x16x32_bf16(
            ah[fm], bh[fn], acc[fm][fn], 0, 0, 0);
        acc[fm][fn] = __builtin_amdgcn_mfma_f32_16x16x32_bf16(
            ah[fm], bl[fn], acc[fm][fn], 0, 0, 0);
        acc[fm][fn] = __builtin_amdgcn_mfma_f32_16x16x32_bf16(
            al[fm], bh[fn], acc[fm][fn], 0, 0, 0);
      }
    __syncthreads();
  }

  // --- epilogue: D col = lane&15 (x), rows = (lane>>4)*4 + reg (oc) [m89] ---
  const int mr4 = (lane >> 4) * 4;
  const int nn  = lane & 15;
  const int hh = y >> 3, ws1 = y & 7;
#pragma unroll
  for (int fm = 0; fm < 4; ++fm) {
    const int oc = oc0 + m0w + fm * 16 + mr4;    // oc..oc+3, same 32-block
    const float4 b4 = *reinterpret_cast<const float4*>(&bias[oc]);
    const int qkvi = oc >> 8;
    const int head = (oc >> 5) & 7;
    const int d0 = oc & 31;                       // multiple of 4
#pragma unroll
    for (int fn = 0; fn < 4; ++fn) {
      const int x = n0w + fn * 16 + nn;
      const int win = hh * 16 + (x >> 3);
      const int pos = ws1 * 8 + (x & 7);
      const size_t addr =
          ((((size_t)qkvi * NWIN_ + win) * NH_ + head) * 64 + pos) * 32 + d0;
      float4 v;
      v.x = acc[fm][fn].x + b4.x;
      v.y = acc[fm][fn].y + b4.y;
      v.z = acc[fm][fn].z + b4.z;
      v.w = acc[fm][fn].w + b4.w;
      *reinterpret_cast<float4*>(&qkv_s[addr]) = v;
    }
  }
}

// ---------------------------------------------------------------------------
// K2 (ALL batches, blockIdx.z = bb): grouped 3x3 conv + bias + BN + ReLU
// ---------------------------------------------------------------------------
__global__ __launch_bounds__(256) void k2_local(
    const float* __restrict__ x, const float* __restrict__ lw,
    const float* __restrict__ lb, const float* __restrict__ bng,
    const float* __restrict__ bnb, float* __restrict__ local_buf) {
  __shared__ float xt[18 * 35];
  __shared__ float wl[288];
  const int tid = threadIdx.x;
  const int g = blockIdx.y;
  const int bb = blockIdx.z;
  const int ty0 = (blockIdx.x >> 2) * 16;
  const int tx0 = (blockIdx.x & 3) * 32;
  const int py = tid >> 4;
  const int px = (tid & 15) * 2;
  const float* xb = x + (size_t)bb * C_ * HW_;

  float acc0[32], acc1[32];
#pragma unroll
  for (int oc = 0; oc < 32; ++oc) { acc0[oc] = 0.f; acc1[oc] = 0.f; }

  for (int ic = 0; ic < 32; ++ic) {
    __syncthreads();
    const float* xp = xb + (size_t)(g * 32 + ic) * HW_;
    for (int i = tid; i < 18 * 34; i += 256) {
      const int r = i / 34, cc = i % 34;
      const int gy = ty0 + r - 1, gx = tx0 + cc - 1;
      float v = 0.f;
      if (gy >= 0 && gy < H_ && gx >= 0 && gx < W_) v = xp[gy * W_ + gx];
      xt[r * 35 + cc] = v;
    }
    for (int i = tid; i < 288; i += 256) {
      const int oc = i / 9, k = i % 9;
      wl[i] = lw[((size_t)(g * 32 + oc) * 32 + ic) * 9 + k];
    }
    __syncthreads();
    float nb[3][4];
#pragma unroll
    for (int dy = 0; dy < 3; ++dy)
#pragma unroll
      for (int dx = 0; dx < 4; ++dx) nb[dy][dx] = xt[(py + dy) * 35 + px + dx];
#pragma unroll
    for (int oc = 0; oc < 32; ++oc) {
      const float* wp = &wl[oc * 9];
      float s0 = 0.f, s1 = 0.f;
#pragma unroll
      for (int dy = 0; dy < 3; ++dy)
#pragma unroll
        for (int dx = 0; dx < 3; ++dx) {
          const float wv = wp[dy * 3 + dx];
          s0 = fmaf(nb[dy][dx], wv, s0);
          s1 = fmaf(nb[dy][dx + 1], wv, s1);
        }
      acc0[oc] += s0;
      acc1[oc] += s1;
    }
  }

  const int gy = ty0 + py;
#pragma unroll
  for (int oc = 0; oc < 32; ++oc) {
    const int c = g * 32 + oc;
    const float scale = bng[c] / sqrtf(1.0f + EPS_);
    const float cb = lb[c], sb = bnb[c];
    const float v0 = fmaxf(fmaf(acc0[oc] + cb, scale, sb), 0.f);
    const float v1 = fmaxf(fmaf(acc1[oc] + cb, scale, sb), 0.f);
    *reinterpret_cast<float2*>(
        &local_buf[((size_t)(bb * C_ + c)) * HW_ + gy * W_ + tx0 + px]) =
        make_float2(v0, v1);
  }
}

// ---------------------------------------------------------------------------
// K3 (per batch): window attention. 1 wave = 1 (window, head). lane = query.
// ---------------------------------------------------------------------------
__global__ __launch_bounds__(128) void k3_attn(
    const float* __restrict__ qkv_s, const float* __restrict__ rpb,
    float* __restrict__ attn_s) {
  __shared__ float kvs[2][2][64 * 32];
  __shared__ float rpb_s[225 * 8];
  const int tid = threadIdx.x;
  const int wid = tid >> 6, lane = tid & 63;
  const int pid = blockIdx.x * 2 + wid;
  const int win = pid >> 3, h = pid & 7;
  const int hh = win >> 4, ww = win & 15;

  for (int i = tid; i < 225 * 8; i += 128) rpb_s[i] = rpb[i];

  const size_t qbase = (((size_t)0 * NWIN_ + win) * NH_ + h) * 2048;
  const size_t kbase = (((size_t)1 * NWIN_ + win) * NH_ + h) * 2048;
  const size_t vbase = (((size_t)2 * NWIN_ + win) * NH_ + h) * 2048;

  float* Kl = kvs[wid][0];
  float* Vl = kvs[wid][1];
#pragma unroll
  for (int r = 0; r < 8; ++r) {
    const int e = r * 256 + lane * 4;
    *reinterpret_cast<float4*>(&Kl[e]) =
        *reinterpret_cast<const float4*>(&qkv_s[kbase + e]);
    *reinterpret_cast<float4*>(&Vl[e]) =
        *reinterpret_cast<const float4*>(&qkv_s[vbase + e]);
  }
  float4 qreg[8];
#pragma unroll
  for (int dd = 0; dd < 8; ++dd)
    qreg[dd] = *reinterpret_cast<const float4*>(&qkv_s[qbase + lane * 32 + dd * 4]);

  __syncthreads();

  float s[64];
#pragma unroll
  for (int j = 0; j < 64; ++j) {
    const float* kr = &Kl[j * 32];
    float sj = 0.f;
#pragma unroll
    for (int dd = 0; dd < 8; ++dd) {
      const float4 kv = *reinterpret_cast<const float4*>(&kr[dd * 4]);
      sj = fmaf(qreg[dd].x, kv.x, sj);
      sj = fmaf(qreg[dd].y, kv.y, sj);
      sj = fmaf(qreg[dd].z, kv.z, sj);
      sj = fmaf(qreg[dd].w, kv.w, sj);
    }
    s[j] = sj;
  }

  const float scale = 0.17677669529663687f;  // 32^-0.5
  const int r1 = lane >> 3, c1 = lane & 7;
  float m = -1e30f;
#pragma unroll
  for (int j = 0; j < 64; ++j) {
    const int jr = j >> 3, jc = j & 7;
    const int idx = (r1 - jr + 7) * 15 + (c1 - jc + 7);
    s[j] = fmaf(s[j], scale, rpb_s[idx * 8 + h]);
    m = fmaxf(m, s[j]);
  }
  float sum = 0.f;
#pragma unroll
  for (int j = 0; j < 64; ++j) {
    s[j] = __expf(s[j] - m);
    sum += s[j];
  }
  const float inv = 1.0f / sum;

  float o[32];
#pragma unroll
  for (int d = 0; d < 32; ++d) o[d] = 0.f;
#pragma unroll
  for (int j = 0; j < 64; ++j) {
    const float pj = s[j] * inv;
    const float* vr = &Vl[j * 32];
#pragma unroll
    for (int dd = 0; dd < 8; ++dd) {
      const float4 vv = *reinterpret_cast<const float4*>(&vr[dd * 4]);
      o[dd * 4 + 0] = fmaf(pj, vv.x, o[dd * 4 + 0]);
      o[dd * 4 + 1] = fmaf(pj, vv.y, o[dd * 4 + 1]);
      o[dd * 4 + 2] = fmaf(pj, vv.z, o[dd * 4 + 2]);
      o[dd * 4 + 3] = fmaf(pj, vv.w, o[dd * 4 + 3]);
    }
  }

  const int yy = hh * 8 + r1, xx = ww * 8 + c1;
  const size_t obase = ((size_t)(h * 32) * H_ + yy) * W_ + xx;
#pragma unroll
  for (int d = 0; d < 32; ++d) attn_s[obase + (size_t)d * HW_] = o[d];
}

// ---------------------------------------------------------------------------
// K4 (per batch): ax (8x1 pool, reflect-bottom) + ay (1x8, reflect-right)
//                 + local; writes pool IN-PLACE over local slice (same idx)
// ---------------------------------------------------------------------------
__global__ __launch_bounds__(256) void k4_pool(
    const float* __restrict__ attn_s, float* __restrict__ localpool) {
  const int bid = blockIdx.x;
  const int c = bid >> 6;
  const int rp = bid & 63;
  const int i = rp * 2 + (threadIdx.x >> 7);
  const int j = threadIdx.x & 127;
  const float* ap = attn_s + (size_t)c * HW_;
  float sx = 0.f;
#pragma unroll
  for (int dr = -3; dr <= 4; ++dr) {
    int r = i + dr;
    if (r < 0 || r > 128) continue;
    if (r == 128) r = 126;
    sx += ap[r * W_ + j];
  }
  float sy = 0.f;
#pragma unroll
  for (int dc = -3; dc <= 4; ++dc) {
    int cc = j + dc;
    if (cc < 0 || cc > 128) continue;
    if (cc == 128) cc = 126;
    sy += ap[i * W_ + cc];
  }
  const size_t idx = (size_t)c * HW_ + i * W_ + j;
  localpool[idx] = (sx + sy) * 0.125f + localpool[idx];
}

// ---------------------------------------------------------------------------
// K5 (per batch): depthwise 3x3 on reflect(0,1,0,1)-padded pool + bias + BN
// ---------------------------------------------------------------------------
__global__ __launch_bounds__(256) void k5_dw(
    const float* __restrict__ pool, const float* __restrict__ dww,
    const float* __restrict__ dwb, const float* __restrict__ bng,
    const float* __restrict__ bnb, float* __restrict__ dwout) {
  const int bid = blockIdx.x;
  const int c = bid >> 6;
  const int rp = bid & 63;
  const int i = rp * 2 + (threadIdx.x >> 7);
  const int j = threadIdx.x & 127;
  const float* pp = pool + (size_t)c * HW_;
  const float* wp = dww + c * 9;
  float acc = 0.f;
#pragma unroll
  for (int dy = 0; dy < 3; ++dy) {
    int r = i + dy - 1;
    if (r < 0) continue;
    if (r == 128) r = 126;
#pragma unroll
    for (int dx = 0; dx < 3; ++dx) {
      int cc = j + dx - 1;
      if (cc < 0) continue;
      if (cc == 128) cc = 126;
      acc = fmaf(wp[dy * 3 + dx], pp[r * W_ + cc], acc);
    }
  }
  const float scale = bng[c] / sqrtf(1.0f + EPS_);
  dwout[(size_t)c * HW_ + i * W_ + j] = fmaf(acc + dwb[c], scale, bnb[c]);
}

// ---------------------------------------------------------------------------
// K6 (per batch): pointwise 1x1 conv GEMM (BK=32, fp32 control) -> d_out slice
// ---------------------------------------------------------------------------
__global__ __launch_bounds__(256) void k6_pw_gemm(
    const float* __restrict__ xin, const float* __restrict__ wp,
    const float* __restrict__ bias, float* __restrict__ outb) {
  __shared__ float s_w[32][64];
  __shared__ float s_x[32][64];
  const int tid = threadIdx.x;
  const int tx = tid & 15, ty = tid >> 4;
  const int p0 = blockIdx.x * 64;
  const int oc0 = blockIdx.y * 64;

  const int m = tid >> 2;
  const int kg = (tid & 3) * 4;
  const int kkld = tid >> 4;
  const int cg = (tid & 15) * 4;

  float acc[4][4];
#pragma unroll
  for (int i = 0; i < 4; ++i)
#pragma unroll
    for (int j = 0; j < 4; ++j) acc[i][j] = 0.f;

  for (int k0 = 0; k0 < 256; k0 += 32) {
    const float4 w0 = *reinterpret_cast<const float4*>(
        &wp[(size_t)(oc0 + m) * 256 + k0 + kg]);
    const float4 w1 = *reinterpret_cast<const float4*>(
        &wp[(size_t)(oc0 + m) * 256 + k0 + kg + 16]);
    const float4 x0 = *reinterpret_cast<const float4*>(
        &xin[(size_t)(k0 + kkld) * HW_ + p0 + cg]);
    const float4 x1 = *reinterpret_cast<const float4*>(
        &xin[(size_t)(k0 + kkld + 16) * HW_ + p0 + cg]);
    s_w[kg + 0][m] = w0.x;  s_w[kg + 1][m] = w0.y;
    s_w[kg + 2][m] = w0.z;  s_w[kg + 3][m] = w0.w;
    s_w[kg + 16][m] = w1.x; s_w[kg + 17][m] = w1.y;
    s_w[kg + 18][m] = w1.z; s_w[kg + 19][m] = w1.w;
    *reinterpret_cast<float4*>(&s_x[kkld][cg]) = x0;
    *reinterpret_cast<float4*>(&s_x[kkld + 16][cg]) = x1;
    __syncthreads();
#pragma unroll
    for (int kk = 0; kk < 32; ++kk) {
      const float4 a = *reinterpret_cast<const float4*>(&s_w[kk][ty * 4]);
      const float4 bv = *reinterpret_cast<const float4*>(&s_x[kk][tx * 4]);
      acc[0][0] = fmaf(a.x, bv.x, acc[0][0]);
      acc[0][1] = fmaf(a.x, bv.y, acc[0][1]);
      acc[0][2] = fmaf(a.x, bv.z, acc[0][2]);
      acc[0][3] = fmaf(a.x, bv.w, acc[0][3]);
      acc[1][0] = fmaf(a.y, bv.x, acc[1][0]);
      acc[1][1] = fmaf(a.y, bv.y, acc[1][1]);
      acc[1][2] = fmaf(a.y, bv.z, acc[1][2]);
      acc[1][3] = fmaf(a.y, bv.w, acc[1][3]);
      acc[2][0] = fmaf(a.z, bv.x, acc[2][0]);
      acc[2][1] = fmaf(a.z, bv.y, acc[2][1]);
      acc[2][2] = fmaf(a.z, bv.z, acc[2][2]);
      acc[2][3] = fmaf(a.z, bv.w, acc[2][3]);
      acc[3][0] = fmaf(a.w, bv.x, acc[3][0]);
      acc[3][1] = fmaf(a.w, bv.y, acc[3][1]);
      acc[3][2] = fmaf(a.w, bv.z, acc[3][2]);
      acc[3][3] = fmaf(a.w, bv.w, acc[3][3]);
    }
    __syncthreads();
  }

#pragma unroll
  for (int i = 0; i < 4; ++i) {
    const int oc = oc0 + ty * 4 + i;
    const float bo = bias[oc];
    float4 v;
    v.x = acc[i][0] + bo;
    v.y = acc[i][1] + bo;
    v.z = acc[i][2] + bo;
    v.w = acc[i][3] + bo;
    *reinterpret_cast<float4*>(&outb[(size_t)oc * HW_ + p0 + tx * 4]) = v;
  }
}

// ---------------------------------------------------------------------------
extern "C" void kernel_launch(void* const* d_in, const int* in_sizes, int n_in,
                              void* d_out, int out_size, void* d_ws, size_t ws_size,
                              hipStream_t stream) {
  const float* x          = (const float*)d_in[0];
  const float* qkv_w      = (const float*)d_in[1];
  const float* qkv_b      = (const float*)d_in[2];
  const float* local_w    = (const float*)d_in[3];
  const float* local_b    = (const float*)d_in[4];
  const float* local_bn_g = (const float*)d_in[5];
  const float* local_bn_b = (const float*)d_in[6];
  const float* rpb        = (const float*)d_in[7];
  const float* proj_dw_w  = (const float*)d_in[8];
  const float* proj_dw_b  = (const float*)d_in[9];
  const float* proj_bn_g  = (const float*)d_in[10];
  const float* proj_bn_b  = (const float*)d_in[11];
  const float* proj_pw_w  = (const float*)d_in[12];
  const float* proj_pw_b  = (const float*)d_in[13];
  float* out = (float*)d_out;
  float* ws = (float*)d_ws;

  const size_t CHW = (size_t)C_ * HW_;                     // 4.19M floats / image
  const size_t NEED_BATCHED  = (8 + 3 + 1) * CHW * 4;      // 201 MB
  const size_t NEED_FALLBACK = (3 + 2) * CHW * 4;          //  84 MB

  if (ws_size >= NEED_BATCHED) {
    // -------- preferred path: k2 batched into one dispatch --------
    float* local_all = ws;               // [8*CHW]  local -> pool (in-place)
    float* qkv_s     = ws + 8 * CHW;     // [3*CHW]  per-batch qkv
    float* attn_s    = qkv_s + 3 * CHW;  // [CHW]    attn -> dw (per batch)

    k2_local<<<dim3(32, NH_, 8), 256, 0, stream>>>(
        x, local_w, local_b, local_bn_g, local_bn_b, local_all);
    for (int bb = 0; bb < 8; ++bb) {
      const float* xb = x + (size_t)bb * CHW;
      float* outb = out + (size_t)bb * CHW;
      float* local_s = local_all + (size_t)bb * CHW;
      k1_qkv_mfma<<<dim3(128, 6), 256, 0, stream>>>(xb, qkv_w, qkv_b, qkv_s);
      k3_attn<<<dim3(1024), 128, 0, stream>>>(qkv_s, rpb, attn_s);
      k4_pool<<<dim3(C_ * 64), 256, 0, stream>>>(attn_s, local_s);
      k5_dw<<<dim3(C_ * 64), 256, 0, stream>>>(local_s, proj_dw_w, proj_dw_b,
                                               proj_bn_g, proj_bn_b, attn_s);
      k6_pw_gemm<<<dim3(256, 4), 256, 0, stream>>>(attn_s, proj_pw_w, proj_pw_b, outb);
    }
  } else {
    if (ws_size < NEED_FALLBACK) return;  // diagnosable fail, no mem-fault
    // -------- fallback: per-batch k2 (round-2 behavior) --------
    float* qkv_s   = ws;
    float* attn_s  = ws + 3 * CHW;
    float* local_s = attn_s + CHW;
    for (int bb = 0; bb < 8; ++bb) {
      const float* xb = x + (size_t)bb * CHW;
      float* outb = out + (size_t)bb * CHW;
      k1_qkv_mfma<<<dim3(128, 6), 256, 0, stream>>>(xb, qkv_w, qkv_b, qkv_s);
      k2_local<<<dim3(32, NH_, 1), 256, 0, stream>>>(
          xb, local_w, local_b, local_bn_g, local_bn_b, local_s);
      k3_attn<<<dim3(1024), 128, 0, stream>>>(qkv_s, rpb, attn_s);
      k4_pool<<<dim3(C_ * 64), 256, 0, stream>>>(attn_s, local_s);
      k5_dw<<<dim3(C_ * 64), 256, 0, stream>>>(local_s, proj_dw_w, proj_dw_b,
                                               proj_bn_g, proj_bn_b, attn_s);
      k6_pw_gemm<<<dim3(256, 4), 256, 0, stream>>>(attn_s, proj_pw_w, proj_pw_b, outb);
    }
  }
}

// Round 7
// 1914.215 us; speedup vs baseline: 1.4839x; 1.1167x over previous
//
#include <hip/hip_runtime.h>
#include <cstddef>

#define C_ 256
#define H_ 128
#define W_ 128
#define HW_ 16384
#define NH_ 8
#define NWIN_ 256   // windows per batch image (16x16)
#define EPS_ 1e-5f

typedef short s16x8 __attribute__((ext_vector_type(8)));
typedef float f32x4 __attribute__((ext_vector_type(4)));

// RNE fp32 -> bf16(hi) + bf16(lo residual). f finite.
__device__ inline void bf16_split(float f, short& h, short& l) {
  unsigned u = __float_as_uint(f);
  unsigned hb = (u + 0x7FFFu + ((u >> 16) & 1u)) >> 16;
  float hf = __uint_as_float(hb << 16);
  h = (short)hb;
  float r = f - hf;                       // exact (Sterbenz)
  unsigned v = __float_as_uint(r);
  unsigned lb = (v + 0x7FFFu + ((v >> 16) & 1u)) >> 16;
  l = (short)lb;
}

// ---------------------------------------------------------------------------
// K1 (per batch): qkv 1x1 conv as split-bf16 MFMA GEMM (PASSED round 6).
// ---------------------------------------------------------------------------
__global__ __launch_bounds__(256) void k1_qkv_mfma(
    const float* __restrict__ xb, const float* __restrict__ wq,
    const float* __restrict__ bias, float* __restrict__ qkv_s) {
  __shared__ short s_a[2][128][40];   // [hi/lo][oc][k]
  __shared__ short s_b[2][128][40];   // [hi/lo][p][k]  (X transposed)
  const int tid = threadIdx.x;
  const int y   = blockIdx.x;          // image row; p0 = y*128
  const int oc0 = blockIdx.y * 128;

  const int lane = tid & 63;
  const int wid  = tid >> 6;
  const int m0w = (wid >> 1) * 64;     // wave row offset (oc)
  const int n0w = (wid & 1) * 64;      // wave col offset (p/x)

  f32x4 acc[4][4];
#pragma unroll
  for (int i = 0; i < 4; ++i)
#pragma unroll
    for (int j = 0; j < 4; ++j) acc[i][j] = f32x4{0.f, 0.f, 0.f, 0.f};

  const int pcol = tid & 127;          // p index for B staging
  const int kq0  = tid >> 7;           // 0..1

  for (int k0 = 0; k0 < 256; k0 += 32) {
    // --- stage A: W[oc0..+127][k0..+31] -> s_a (hi/lo) ---
#pragma unroll
    for (int i = 0; i < 4; ++i) {
      const int ff = tid + i * 256;
      const int row = ff >> 3;
      const int c4 = ff & 7;
      const float4 w4 = *reinterpret_cast<const float4*>(
          &wq[(size_t)(oc0 + row) * 256 + k0 + c4 * 4]);
      short h0, h1, h2, h3, l0, l1, l2, l3;
      bf16_split(w4.x, h0, l0);
      bf16_split(w4.y, h1, l1);
      bf16_split(w4.z, h2, l2);
      bf16_split(w4.w, h3, l3);
      *reinterpret_cast<short4*>(&s_a[0][row][c4 * 4]) = make_short4(h0, h1, h2, h3);
      *reinterpret_cast<short4*>(&s_a[1][row][c4 * 4]) = make_short4(l0, l1, l2, l3);
    }
    // --- stage B: X[k0..+31][y*128 + 0..127] -> s_b transposed (hi/lo) ---
#pragma unroll
    for (int it = 0; it < 4; ++it) {
      const int kq = kq0 * 4 + it;
      short h[4], l[4];
#pragma unroll
      for (int e = 0; e < 4; ++e) {
        const float v = xb[(size_t)(k0 + kq * 4 + e) * HW_ + y * W_ + pcol];
        bf16_split(v, h[e], l[e]);
      }
      *reinterpret_cast<short4*>(&s_b[0][pcol][kq * 4]) = make_short4(h[0], h[1], h[2], h[3]);
      *reinterpret_cast<short4*>(&s_b[1][pcol][kq * 4]) = make_short4(l[0], l[1], l[2], l[3]);
    }
    __syncthreads();

    const int mr = lane & 15;
    const int kg = (lane >> 4) * 8;
    s16x8 ah[4], al[4], bh[4], bl[4];
#pragma unroll
    for (int fm = 0; fm < 4; ++fm) {
      ah[fm] = *reinterpret_cast<const s16x8*>(&s_a[0][m0w + fm * 16 + mr][kg]);
      al[fm] = *reinterpret_cast<const s16x8*>(&s_a[1][m0w + fm * 16 + mr][kg]);
    }
#pragma unroll
    for (int fn = 0; fn < 4; ++fn) {
      bh[fn] = *reinterpret_cast<const s16x8*>(&s_b[0][n0w + fn * 16 + mr][kg]);
      bl[fn] = *reinterpret_cast<const s16x8*>(&s_b[1][n0w + fn * 16 + mr][kg]);
    }
#pragma unroll
    for (int fm = 0; fm < 4; ++fm)
#pragma unroll
      for (int fn = 0; fn < 4; ++fn) {
        acc[fm][fn] = __builtin_amdgcn_mfma_f32_16x16x32_bf16(
            ah[fm], bh[fn], acc[fm][fn], 0, 0, 0);
        acc[fm][fn] = __builtin_amdgcn_mfma_f32_16x16x32_bf16(
            ah[fm], bl[fn], acc[fm][fn], 0, 0, 0);
        acc[fm][fn] = __builtin_amdgcn_mfma_f32_16x16x32_bf16(
            al[fm], bh[fn], acc[fm][fn], 0, 0, 0);
      }
    __syncthreads();
  }

  const int mr4 = (lane >> 4) * 4;
  const int nn  = lane & 15;
  const int hh = y >> 3, ws1 = y & 7;
#pragma unroll
  for (int fm = 0; fm < 4; ++fm) {
    const int oc = oc0 + m0w + fm * 16 + mr4;
    const float4 b4 = *reinterpret_cast<const float4*>(&bias[oc]);
    const int qkvi = oc >> 8;
    const int head = (oc >> 5) & 7;
    const int d0 = oc & 31;
#pragma unroll
    for (int fn = 0; fn < 4; ++fn) {
      const int x = n0w + fn * 16 + nn;
      const int win = hh * 16 + (x >> 3);
      const int pos = ws1 * 8 + (x & 7);
      const size_t addr =
          ((((size_t)qkvi * NWIN_ + win) * NH_ + head) * 64 + pos) * 32 + d0;
      float4 v;
      v.x = acc[fm][fn].x + b4.x;
      v.y = acc[fm][fn].y + b4.y;
      v.z = acc[fm][fn].z + b4.z;
      v.w = acc[fm][fn].w + b4.w;
      *reinterpret_cast<float4*>(&qkv_s[addr]) = v;
    }
  }
}

// ---------------------------------------------------------------------------
// K2a: transform grouped-conv weights -> WT[g][tau][hl][oc 32][ic 32] bf16
// ---------------------------------------------------------------------------
__global__ __launch_bounds__(256) void k2_wt(
    const float* __restrict__ lw, short* __restrict__ WT) {
  const int i = blockIdx.x * 256 + threadIdx.x;   // 8*9*32*32 = 73728
  if (i >= 73728) return;
  const int g = i / 9216;
  const int rem = i % 9216;
  const int tau = rem / 1024;
  const int oc = (rem >> 5) & 31;
  const int ic = rem & 31;
  const float w = lw[((size_t)(g * 32 + oc) * 32 + ic) * 9 + tau];
  short h, l;
  bf16_split(w, h, l);
  WT[((g * 9 + tau) * 2 + 0) * 1024 + oc * 32 + ic] = h;
  WT[((g * 9 + tau) * 2 + 1) * 1024 + oc * 32 + ic] = l;
}

// ---------------------------------------------------------------------------
// K2 (ALL batches): grouped 3x3 conv as 9 shifted split-bf16 MFMA GEMMs
//   + bias + BN(eval) + ReLU.
//   Block = (row y, group g, batch b). M=32 oc, N=128 px, K=9tau x 32ic.
//   LDS xt[3 rows][132 px-slots][64]: idx (hl*32+ic)^((slot&7)*8) — 3-bit XOR
//   swizzle -> conflict-free ds_read_b128 B-frags at any tap shift.
//   4 waves x 32 px; per wave 2m x 2n frags; 9 x 12 MFMAs.
// ---------------------------------------------------------------------------
__global__ __launch_bounds__(256) void k2_mfma(
    const float* __restrict__ x, const short* __restrict__ WT,
    const float* __restrict__ lb, const float* __restrict__ bng,
    const float* __restrict__ bnb, float* __restrict__ local_buf) {
  __shared__ short xt[3][132][64];
  const int tid = threadIdx.x;
  const int y = blockIdx.x;
  const int g = blockIdx.y;
  const int bb = blockIdx.z;

  // --- stage 3 rows x 130 px (px=-1..128) x 32 ic, hi/lo, swizzled ---
  for (int i = tid; i < 12480; i += 256) {        // 3*32*130
    const int r = i / 4160;                        // 32*130
    const int rem = i - r * 4160;
    const int ic = rem / 130;
    const int px = rem - ic * 130 - 1;             // -1..128
    const int gy = y + r - 1;
    float v = 0.f;
    if (gy >= 0 && gy < H_ && px >= 0 && px < W_)
      v = x[(((size_t)(bb * C_ + g * 32 + ic)) * H_ + gy) * W_ + px];
    short h, l;
    bf16_split(v, h, l);
    const int slot = px + 1;                       // 0..129
    const int sw = (slot & 7) * 8;
    xt[r][slot][(ic) ^ sw] = h;
    xt[r][slot][(32 + ic) ^ sw] = l;
  }
  __syncthreads();

  const int lane = tid & 63;
  const int wid = tid >> 6;
  const int px0w = wid * 32;
  const int mr = lane & 15;
  const int kg = (lane >> 4) * 8;

  f32x4 acc[2][2];
#pragma unroll
  for (int i = 0; i < 2; ++i)
#pragma unroll
    for (int j = 0; j < 2; ++j) acc[i][j] = f32x4{0.f, 0.f, 0.f, 0.f};

#pragma unroll
  for (int tau = 0; tau < 9; ++tau) {
    const int dy = tau / 3;
    const int dx = tau % 3;
    // A frags from WT (global, L2-hot): [g][tau][hl][oc][ic]
    const int wt0 = ((g * 9 + tau) * 2) * 1024;
    s16x8 ah[2], al[2], bh[2], bl[2];
#pragma unroll
    for (int fm = 0; fm < 2; ++fm) {
      ah[fm] = *reinterpret_cast<const s16x8*>(&WT[wt0 + (fm * 16 + mr) * 32 + kg]);
      al[fm] = *reinterpret_cast<const s16x8*>(&WT[wt0 + 1024 + (fm * 16 + mr) * 32 + kg]);
    }
#pragma unroll
    for (int fn = 0; fn < 2; ++fn) {
      const int slot = px0w + fn * 16 + mr + dx;   // px_out + dx, 0..129
      const int sw = (slot & 7) * 8;
      bh[fn] = *reinterpret_cast<const s16x8*>(&xt[dy][slot][(kg) ^ sw]);
      bl[fn] = *reinterpret_cast<const s16x8*>(&xt[dy][slot][(32 + kg) ^ sw]);
    }
#pragma unroll
    for (int fm = 0; fm < 2; ++fm)
#pragma unroll
      for (int fn = 0; fn < 2; ++fn) {
        acc[fm][fn] = __builtin_amdgcn_mfma_f32_16x16x32_bf16(
            ah[fm], bh[fn], acc[fm][fn], 0, 0, 0);
        acc[fm][fn] = __builtin_amdgcn_mfma_f32_16x16x32_bf16(
            ah[fm], bl[fn], acc[fm][fn], 0, 0, 0);
        acc[fm][fn] = __builtin_amdgcn_mfma_f32_16x16x32_bf16(
            al[fm], bh[fn], acc[fm][fn], 0, 0, 0);
      }
  }

  // --- epilogue: bias + BN + ReLU, NCHW ---
  const int mr4 = (lane >> 4) * 4;
  const float inv_s = 1.0f / sqrtf(1.0f + EPS_);
#pragma unroll
  for (int fm = 0; fm < 2; ++fm)
#pragma unroll
    for (int r = 0; r < 4; ++r) {
      const int c = g * 32 + fm * 16 + mr4 + r;
      const float scale = bng[c] * inv_s;
      const float cb = lb[c], sb = bnb[c];
#pragma unroll
      for (int fn = 0; fn < 2; ++fn) {
        const int px = px0w + fn * 16 + mr;
        const float val = fmaxf(fmaf(acc[fm][fn][r] + cb, scale, sb), 0.f);
        local_buf[(((size_t)(bb * C_ + c)) * H_ + y) * W_ + px] = val;
      }
    }
}

// ---------------------------------------------------------------------------
// K3 (per batch): window attention. 1 wave = 1 (window, head). lane = query.
// ---------------------------------------------------------------------------
__global__ __launch_bounds__(128) void k3_attn(
    const float* __restrict__ qkv_s, const float* __restrict__ rpb,
    float* __restrict__ attn_s) {
  __shared__ float kvs[2][2][64 * 32];
  __shared__ float rpb_s[225 * 8];
  const int tid = threadIdx.x;
  const int wid = tid >> 6, lane = tid & 63;
  const int pid = blockIdx.x * 2 + wid;
  const int win = pid >> 3, h = pid & 7;
  const int hh = win >> 4, ww = win & 15;

  for (int i = tid; i < 225 * 8; i += 128) rpb_s[i] = rpb[i];

  const size_t qbase = (((size_t)0 * NWIN_ + win) * NH_ + h) * 2048;
  const size_t kbase = (((size_t)1 * NWIN_ + win) * NH_ + h) * 2048;
  const size_t vbase = (((size_t)2 * NWIN_ + win) * NH_ + h) * 2048;

  float* Kl = kvs[wid][0];
  float* Vl = kvs[wid][1];
#pragma unroll
  for (int r = 0; r < 8; ++r) {
    const int e = r * 256 + lane * 4;
    *reinterpret_cast<float4*>(&Kl[e]) =
        *reinterpret_cast<const float4*>(&qkv_s[kbase + e]);
    *reinterpret_cast<float4*>(&Vl[e]) =
        *reinterpret_cast<const float4*>(&qkv_s[vbase + e]);
  }
  float4 qreg[8];
#pragma unroll
  for (int dd = 0; dd < 8; ++dd)
    qreg[dd] = *reinterpret_cast<const float4*>(&qkv_s[qbase + lane * 32 + dd * 4]);

  __syncthreads();

  float s[64];
#pragma unroll
  for (int j = 0; j < 64; ++j) {
    const float* kr = &Kl[j * 32];
    float sj = 0.f;
#pragma unroll
    for (int dd = 0; dd < 8; ++dd) {
      const float4 kv = *reinterpret_cast<const float4*>(&kr[dd * 4]);
      sj = fmaf(qreg[dd].x, kv.x, sj);
      sj = fmaf(qreg[dd].y, kv.y, sj);
      sj = fmaf(qreg[dd].z, kv.z, sj);
      sj = fmaf(qreg[dd].w, kv.w, sj);
    }
    s[j] = sj;
  }

  const float scale = 0.17677669529663687f;  // 32^-0.5
  const int r1 = lane >> 3, c1 = lane & 7;
  float m = -1e30f;
#pragma unroll
  for (int j = 0; j < 64; ++j) {
    const int jr = j >> 3, jc = j & 7;
    const int idx = (r1 - jr + 7) * 15 + (c1 - jc + 7);
    s[j] = fmaf(s[j], scale, rpb_s[idx * 8 + h]);
    m = fmaxf(m, s[j]);
  }
  float sum = 0.f;
#pragma unroll
  for (int j = 0; j < 64; ++j) {
    s[j] = __expf(s[j] - m);
    sum += s[j];
  }
  const float inv = 1.0f / sum;

  float o[32];
#pragma unroll
  for (int d = 0; d < 32; ++d) o[d] = 0.f;
#pragma unroll
  for (int j = 0; j < 64; ++j) {
    const float pj = s[j] * inv;
    const float* vr = &Vl[j * 32];
#pragma unroll
    for (int dd = 0; dd < 8; ++dd) {
      const float4 vv = *reinterpret_cast<const float4*>(&vr[dd * 4]);
      o[dd * 4 + 0] = fmaf(pj, vv.x, o[dd * 4 + 0]);
      o[dd * 4 + 1] = fmaf(pj, vv.y, o[dd * 4 + 1]);
      o[dd * 4 + 2] = fmaf(pj, vv.z, o[dd * 4 + 2]);
      o[dd * 4 + 3] = fmaf(pj, vv.w, o[dd * 4 + 3]);
    }
  }

  const int yy = hh * 8 + r1, xx = ww * 8 + c1;
  const size_t obase = ((size_t)(h * 32) * H_ + yy) * W_ + xx;
#pragma unroll
  for (int d = 0; d < 32; ++d) attn_s[obase + (size_t)d * HW_] = o[d];
}

// ---------------------------------------------------------------------------
// K4 (per batch): ax (8x1 pool, reflect-bottom) + ay (1x8, reflect-right)
//                 + local; writes pool IN-PLACE over local slice (same idx)
// ---------------------------------------------------------------------------
__global__ __launch_bounds__(256) void k4_pool(
    const float* __restrict__ attn_s, float* __restrict__ localpool) {
  const int bid = blockIdx.x;
  const int c = bid >> 6;
  const int rp = bid & 63;
  const int i = rp * 2 + (threadIdx.x >> 7);
  const int j = threadIdx.x & 127;
  const float* ap = attn_s + (size_t)c * HW_;
  float sx = 0.f;
#pragma unroll
  for (int dr = -3; dr <= 4; ++dr) {
    int r = i + dr;
    if (r < 0 || r > 128) continue;
    if (r == 128) r = 126;
    sx += ap[r * W_ + j];
  }
  float sy = 0.f;
#pragma unroll
  for (int dc = -3; dc <= 4; ++dc) {
    int cc = j + dc;
    if (cc < 0 || cc > 128) continue;
    if (cc == 128) cc = 126;
    sy += ap[i * W_ + cc];
  }
  const size_t idx = (size_t)c * HW_ + i * W_ + j;
  localpool[idx] = (sx + sy) * 0.125f + localpool[idx];
}

// ---------------------------------------------------------------------------
// K5 (per batch): depthwise 3x3 on reflect(0,1,0,1)-padded pool + bias + BN
// ---------------------------------------------------------------------------
__global__ __launch_bounds__(256) void k5_dw(
    const float* __restrict__ pool, const float* __restrict__ dww,
    const float* __restrict__ dwb, const float* __restrict__ bng,
    const float* __restrict__ bnb, float* __restrict__ dwout) {
  const int bid = blockIdx.x;
  const int c = bid >> 6;
  const int rp = bid & 63;
  const int i = rp * 2 + (threadIdx.x >> 7);
  const int j = threadIdx.x & 127;
  const float* pp = pool + (size_t)c * HW_;
  const float* wp = dww + c * 9;
  float acc = 0.f;
#pragma unroll
  for (int dy = 0; dy < 3; ++dy) {
    int r = i + dy - 1;
    if (r < 0) continue;
    if (r == 128) r = 126;
#pragma unroll
    for (int dx = 0; dx < 3; ++dx) {
      int cc = j + dx - 1;
      if (cc < 0) continue;
      if (cc == 128) cc = 126;
      acc = fmaf(wp[dy * 3 + dx], pp[r * W_ + cc], acc);
    }
  }
  const float scale = bng[c] / sqrtf(1.0f + EPS_);
  dwout[(size_t)c * HW_ + i * W_ + j] = fmaf(acc + dwb[c], scale, bnb[c]);
}

// ---------------------------------------------------------------------------
// K6 (per batch): pointwise 1x1 conv as split-bf16 MFMA GEMM (k1 clone,
//                 NCHW epilogue). M=256, N=16384, K=256. grid (128 y, 2 oct).
// ---------------------------------------------------------------------------
__global__ __launch_bounds__(256) void k6_pw_mfma(
    const float* __restrict__ xin, const float* __restrict__ wq,
    const float* __restrict__ bias, float* __restrict__ outb) {
  __shared__ short s_a[2][128][40];
  __shared__ short s_b[2][128][40];
  const int tid = threadIdx.x;
  const int y   = blockIdx.x;
  const int oc0 = blockIdx.y * 128;

  const int lane = tid & 63;
  const int wid  = tid >> 6;
  const int m0w = (wid >> 1) * 64;
  const int n0w = (wid & 1) * 64;

  f32x4 acc[4][4];
#pragma unroll
  for (int i = 0; i < 4; ++i)
#pragma unroll
    for (int j = 0; j < 4; ++j) acc[i][j] = f32x4{0.f, 0.f, 0.f, 0.f};

  const int pcol = tid & 127;
  const int kq0  = tid >> 7;

  for (int k0 = 0; k0 < 256; k0 += 32) {
#pragma unroll
    for (int i = 0; i < 4; ++i) {
      const int ff = tid + i * 256;
      const int row = ff >> 3;
      const int c4 = ff & 7;
      const float4 w4 = *reinterpret_cast<const float4*>(
          &wq[(size_t)(oc0 + row) * 256 + k0 + c4 * 4]);
      short h0, h1, h2, h3, l0, l1, l2, l3;
      bf16_split(w4.x, h0, l0);
      bf16_split(w4.y, h1, l1);
      bf16_split(w4.z, h2, l2);
      bf16_split(w4.w, h3, l3);
      *reinterpret_cast<short4*>(&s_a[0][row][c4 * 4]) = make_short4(h0, h1, h2, h3);
      *reinterpret_cast<short4*>(&s_a[1][row][c4 * 4]) = make_short4(l0, l1, l2, l3);
    }
#pragma unroll
    for (int it = 0; it < 4; ++it) {
      const int kq = kq0 * 4 + it;
      short h[4], l[4];
#pragma unroll
      for (int e = 0; e < 4; ++e) {
        const float v = xin[(size_t)(k0 + kq * 4 + e) * HW_ + y * W_ + pcol];
        bf16_split(v, h[e], l[e]);
      }
      *reinterpret_cast<short4*>(&s_b[0][pcol][kq * 4]) = make_short4(h[0], h[1], h[2], h[3]);
      *reinterpret_cast<short4*>(&s_b[1][pcol][kq * 4]) = make_short4(l[0], l[1], l[2], l[3]);
    }
    __syncthreads();

    const int mr = lane & 15;
    const int kg = (lane >> 4) * 8;
    s16x8 ah[4], al[4], bh[4], bl[4];
#pragma unroll
    for (int fm = 0; fm < 4; ++fm) {
      ah[fm] = *reinterpret_cast<const s16x8*>(&s_a[0][m0w + fm * 16 + mr][kg]);
      al[fm] = *reinterpret_cast<const s16x8*>(&s_a[1][m0w + fm * 16 + mr][kg]);
    }
#pragma unroll
    for (int fn = 0; fn < 4; ++fn) {
      bh[fn] = *reinterpret_cast<const s16x8*>(&s_b[0][n0w + fn * 16 + mr][kg]);
      bl[fn] = *reinterpret_cast<const s16x8*>(&s_b[1][n0w + fn * 16 + mr][kg]);
    }
#pragma unroll
    for (int fm = 0; fm < 4; ++fm)
#pragma unroll
      for (int fn = 0; fn < 4; ++fn) {
        acc[fm][fn] = __builtin_amdgcn_mfma_f32_16x16x32_bf16(
            ah[fm], bh[fn], acc[fm][fn], 0, 0, 0);
        acc[fm][fn] = __builtin_amdgcn_mfma_f32_16x16x32_bf16(
            ah[fm], bl[fn], acc[fm][fn], 0, 0, 0);
        acc[fm][fn] = __builtin_amdgcn_mfma_f32_16x16x32_bf16(
            al[fm], bh[fn], acc[fm][fn], 0, 0, 0);
      }
    __syncthreads();
  }

  // --- epilogue: NCHW out[oc][y][px], bias ---
  const int mr4 = (lane >> 4) * 4;
  const int nn  = lane & 15;
#pragma unroll
  for (int fm = 0; fm < 4; ++fm) {
    const int ocb = oc0 + m0w + fm * 16 + mr4;
#pragma unroll
    for (int r = 0; r < 4; ++r) {
      const int oc = ocb + r;
      const float bo = bias[oc];
#pragma unroll
      for (int fn = 0; fn < 4; ++fn) {
        const int px = n0w + fn * 16 + nn;
        outb[(size_t)oc * HW_ + y * W_ + px] = acc[fm][fn][r] + bo;
      }
    }
  }
}

// ---------------------------------------------------------------------------
extern "C" void kernel_launch(void* const* d_in, const int* in_sizes, int n_in,
                              void* d_out, int out_size, void* d_ws, size_t ws_size,
                              hipStream_t stream) {
  const float* x          = (const float*)d_in[0];
  const float* qkv_w      = (const float*)d_in[1];
  const float* qkv_b      = (const float*)d_in[2];
  const float* local_w    = (const float*)d_in[3];
  const float* local_b    = (const float*)d_in[4];
  const float* local_bn_g = (const float*)d_in[5];
  const float* local_bn_b = (const float*)d_in[6];
  const float* rpb        = (const float*)d_in[7];
  const float* proj_dw_w  = (const float*)d_in[8];
  const float* proj_dw_b  = (const float*)d_in[9];
  const float* proj_bn_g  = (const float*)d_in[10];
  const float* proj_bn_b  = (const float*)d_in[11];
  const float* proj_pw_w  = (const float*)d_in[12];
  const float* proj_pw_b  = (const float*)d_in[13];
  float* out = (float*)d_out;
  float* ws = (float*)d_ws;

  const size_t CHW = (size_t)C_ * HW_;             // 4.19M floats / image
  const size_t NEED = 12 * CHW * 4;                // 201 MB (proven available)
  if (ws_size < NEED) return;

  float* local_all = ws;               // [8*CHW]  local -> pool (in-place)
  float* qkv_s     = ws + 8 * CHW;     // [3*CHW]  per-batch qkv
  float* attn_s    = qkv_s + 3 * CHW;  // [CHW]    attn -> dw (per batch)
  // WT (288 KB) lives at the start of qkv_s: consumed by k2 (before the batch
  // loop) and only then overwritten by k1 — in-order stream makes this safe.
  short* WT = (short*)qkv_s;

  k2_wt<<<dim3(288), 256, 0, stream>>>(local_w, WT);
  k2_mfma<<<dim3(128, 8, 8), 256, 0, stream>>>(
      x, WT, local_b, local_bn_g, local_bn_b, local_all);

  for (int bb = 0; bb < 8; ++bb) {
    const float* xb = x + (size_t)bb * CHW;
    float* outb = out + (size_t)bb * CHW;
    float* local_s = local_all + (size_t)bb * CHW;
    k1_qkv_mfma<<<dim3(128, 6), 256, 0, stream>>>(xb, qkv_w, qkv_b, qkv_s);
    k3_attn<<<dim3(1024), 128, 0, stream>>>(qkv_s, rpb, attn_s);
    k4_pool<<<dim3(C_ * 64), 256, 0, stream>>>(attn_s, local_s);
    k5_dw<<<dim3(C_ * 64), 256, 0, stream>>>(local_s, proj_dw_w, proj_dw_b,
                                             proj_bn_g, proj_bn_b, attn_s);
    k6_pw_mfma<<<dim3(128, 2), 256, 0, stream>>>(attn_s, proj_pw_w, proj_pw_b, outb);
  }
}

// Round 8
// 1741.552 us; speedup vs baseline: 1.6311x; 1.0991x over previous
//
#include <hip/hip_runtime.h>
#include <cstddef>

#define C_ 256
#define H_ 128
#define W_ 128
#define HW_ 16384
#define NH_ 8
#define NWIN_ 256   // windows per batch image (16x16)
#define EPS_ 1e-5f

typedef short s16x8 __attribute__((ext_vector_type(8)));
typedef float f32x4 __attribute__((ext_vector_type(4)));

// RNE fp32 -> bf16(hi) + bf16(lo residual). f finite.
__device__ inline void bf16_split(float f, short& h, short& l) {
  unsigned u = __float_as_uint(f);
  unsigned hb = (u + 0x7FFFu + ((u >> 16) & 1u)) >> 16;
  float hf = __uint_as_float(hb << 16);
  h = (short)hb;
  float r = f - hf;                       // exact (Sterbenz)
  unsigned v = __float_as_uint(r);
  unsigned lb = (v + 0x7FFFu + ((v >> 16) & 1u)) >> 16;
  l = (short)lb;
}

// ---------------------------------------------------------------------------
// K1 (per batch): qkv 1x1 conv as split-bf16 MFMA GEMM (PASSED r6/r7).
// ---------------------------------------------------------------------------
__global__ __launch_bounds__(256) void k1_qkv_mfma(
    const float* __restrict__ xb, const float* __restrict__ wq,
    const float* __restrict__ bias, float* __restrict__ qkv_s) {
  __shared__ short s_a[2][128][40];   // [hi/lo][oc][k]
  __shared__ short s_b[2][128][40];   // [hi/lo][p][k]  (X transposed)
  const int tid = threadIdx.x;
  const int y   = blockIdx.x;          // image row; p0 = y*128
  const int oc0 = blockIdx.y * 128;

  const int lane = tid & 63;
  const int wid  = tid >> 6;
  const int m0w = (wid >> 1) * 64;     // wave row offset (oc)
  const int n0w = (wid & 1) * 64;      // wave col offset (p/x)

  f32x4 acc[4][4];
#pragma unroll
  for (int i = 0; i < 4; ++i)
#pragma unroll
    for (int j = 0; j < 4; ++j) acc[i][j] = f32x4{0.f, 0.f, 0.f, 0.f};

  const int pcol = tid & 127;          // p index for B staging
  const int kq0  = tid >> 7;           // 0..1

  for (int k0 = 0; k0 < 256; k0 += 32) {
#pragma unroll
    for (int i = 0; i < 4; ++i) {
      const int ff = tid + i * 256;
      const int row = ff >> 3;
      const int c4 = ff & 7;
      const float4 w4 = *reinterpret_cast<const float4*>(
          &wq[(size_t)(oc0 + row) * 256 + k0 + c4 * 4]);
      short h0, h1, h2, h3, l0, l1, l2, l3;
      bf16_split(w4.x, h0, l0);
      bf16_split(w4.y, h1, l1);
      bf16_split(w4.z, h2, l2);
      bf16_split(w4.w, h3, l3);
      *reinterpret_cast<short4*>(&s_a[0][row][c4 * 4]) = make_short4(h0, h1, h2, h3);
      *reinterpret_cast<short4*>(&s_a[1][row][c4 * 4]) = make_short4(l0, l1, l2, l3);
    }
#pragma unroll
    for (int it = 0; it < 4; ++it) {
      const int kq = kq0 * 4 + it;
      short h[4], l[4];
#pragma unroll
      for (int e = 0; e < 4; ++e) {
        const float v = xb[(size_t)(k0 + kq * 4 + e) * HW_ + y * W_ + pcol];
        bf16_split(v, h[e], l[e]);
      }
      *reinterpret_cast<short4*>(&s_b[0][pcol][kq * 4]) = make_short4(h[0], h[1], h[2], h[3]);
      *reinterpret_cast<short4*>(&s_b[1][pcol][kq * 4]) = make_short4(l[0], l[1], l[2], l[3]);
    }
    __syncthreads();

    const int mr = lane & 15;
    const int kg = (lane >> 4) * 8;
    s16x8 ah[4], al[4], bh[4], bl[4];
#pragma unroll
    for (int fm = 0; fm < 4; ++fm) {
      ah[fm] = *reinterpret_cast<const s16x8*>(&s_a[0][m0w + fm * 16 + mr][kg]);
      al[fm] = *reinterpret_cast<const s16x8*>(&s_a[1][m0w + fm * 16 + mr][kg]);
    }
#pragma unroll
    for (int fn = 0; fn < 4; ++fn) {
      bh[fn] = *reinterpret_cast<const s16x8*>(&s_b[0][n0w + fn * 16 + mr][kg]);
      bl[fn] = *reinterpret_cast<const s16x8*>(&s_b[1][n0w + fn * 16 + mr][kg]);
    }
#pragma unroll
    for (int fm = 0; fm < 4; ++fm)
#pragma unroll
      for (int fn = 0; fn < 4; ++fn) {
        acc[fm][fn] = __builtin_amdgcn_mfma_f32_16x16x32_bf16(
            ah[fm], bh[fn], acc[fm][fn], 0, 0, 0);
        acc[fm][fn] = __builtin_amdgcn_mfma_f32_16x16x32_bf16(
            ah[fm], bl[fn], acc[fm][fn], 0, 0, 0);
        acc[fm][fn] = __builtin_amdgcn_mfma_f32_16x16x32_bf16(
            al[fm], bh[fn], acc[fm][fn], 0, 0, 0);
      }
    __syncthreads();
  }

  const int mr4 = (lane >> 4) * 4;
  const int nn  = lane & 15;
  const int hh = y >> 3, ws1 = y & 7;
#pragma unroll
  for (int fm = 0; fm < 4; ++fm) {
    const int oc = oc0 + m0w + fm * 16 + mr4;
    const float4 b4 = *reinterpret_cast<const float4*>(&bias[oc]);
    const int qkvi = oc >> 8;
    const int head = (oc >> 5) & 7;
    const int d0 = oc & 31;
#pragma unroll
    for (int fn = 0; fn < 4; ++fn) {
      const int x = n0w + fn * 16 + nn;
      const int win = hh * 16 + (x >> 3);
      const int pos = ws1 * 8 + (x & 7);
      const size_t addr =
          ((((size_t)qkvi * NWIN_ + win) * NH_ + head) * 64 + pos) * 32 + d0;
      float4 v;
      v.x = acc[fm][fn].x + b4.x;
      v.y = acc[fm][fn].y + b4.y;
      v.z = acc[fm][fn].z + b4.z;
      v.w = acc[fm][fn].w + b4.w;
      *reinterpret_cast<float4*>(&qkv_s[addr]) = v;
    }
  }
}

// ---------------------------------------------------------------------------
// K2a: transform grouped-conv weights -> WT[g][tau][hl][oc 32][ic 32] bf16
// ---------------------------------------------------------------------------
__global__ __launch_bounds__(256) void k2_wt(
    const float* __restrict__ lw, short* __restrict__ WT) {
  const int i = blockIdx.x * 256 + threadIdx.x;   // 8*9*32*32 = 73728
  if (i >= 73728) return;
  const int g = i / 9216;
  const int rem = i % 9216;
  const int tau = rem / 1024;
  const int oc = (rem >> 5) & 31;
  const int ic = rem & 31;
  const float w = lw[((size_t)(g * 32 + oc) * 32 + ic) * 9 + tau];
  short h, l;
  bf16_split(w, h, l);
  WT[((g * 9 + tau) * 2 + 0) * 1024 + oc * 32 + ic] = h;
  WT[((g * 9 + tau) * 2 + 1) * 1024 + oc * 32 + ic] = l;
}

// ---------------------------------------------------------------------------
// K2 (ALL batches): grouped 3x3 conv as 9 shifted split-bf16 MFMA GEMMs.
//   v3: division-free float4 staging; XCD-chunked block swizzle so all 128
//   y-rows of one (g,b) plane (2 MB) stay on one XCD's L2 -> halo re-reads
//   are L2 hits. MFMA/frag-read path identical to the round-7 passing kernel.
//   Grid: 8192 1D. xcd = wg&7 (HW round-robin), each XCD owns 8 (g,b) planes.
// ---------------------------------------------------------------------------
__global__ __launch_bounds__(256) void k2_mfma(
    const float* __restrict__ x, const short* __restrict__ WT,
    const float* __restrict__ lb, const float* __restrict__ bng,
    const float* __restrict__ bnb, float* __restrict__ local_buf) {
  __shared__ short xt[3][132][64];
  const int tid = threadIdx.x;
  const int wg = blockIdx.x;
  const int xcd = wg & 7;
  const int jj = wg >> 3;                 // 0..1023
  const int pair = xcd * 8 + (jj >> 7);   // 0..63 (g,b) plane
  const int y = jj & 127;
  const int g = pair & 7;
  const int bb = pair >> 3;

  // halo columns px=-1 (slot 0) and px=128 (slot 129): always zero (conv pad)
  if (tid < 192) {
    const int r = tid >> 6;               // 0..2
    const int k = tid & 63;
    const int side = k >> 5, ic = k & 31;
    const int slot = side ? 129 : 0;
    const int sw = (slot & 7) * 8;
    xt[r][slot][ic ^ sw] = 0;
    xt[r][slot][(32 + ic) ^ sw] = 0;
  }
  // main: 3 rows x 32 ic x 128 px, float4 loads, all-bit-op indexing
  const int pxq = tid & 31;               // 4-px chunk
#pragma unroll
  for (int it = 0; it < 12; ++it) {
    const int q = it * 8 + (tid >> 5);    // 0..95
    const int r = q >> 5;                 // uniform per it
    const int ic = q & 31;
    const int gy = y + r - 1;
    const int px = pxq * 4;
    float4 v = make_float4(0.f, 0.f, 0.f, 0.f);
    if (gy >= 0 && gy < H_)
      v = *reinterpret_cast<const float4*>(
          &x[(((size_t)(bb * C_ + g * 32 + ic)) * H_ + gy) * W_ + px]);
#pragma unroll
    for (int e = 0; e < 4; ++e) {
      const float f = (&v.x)[e];
      short h, l;
      bf16_split(f, h, l);
      const int slot = px + 1 + e;
      const int sw = (slot & 7) * 8;
      xt[r][slot][ic ^ sw] = h;
      xt[r][slot][(32 + ic) ^ sw] = l;
    }
  }
  __syncthreads();

  const int lane = tid & 63;
  const int wid = tid >> 6;
  const int px0w = wid * 32;
  const int mr = lane & 15;
  const int kg = (lane >> 4) * 8;

  f32x4 acc[2][2];
#pragma unroll
  for (int i = 0; i < 2; ++i)
#pragma unroll
    for (int j = 0; j < 2; ++j) acc[i][j] = f32x4{0.f, 0.f, 0.f, 0.f};

#pragma unroll
  for (int tau = 0; tau < 9; ++tau) {
    const int dy = tau / 3;
    const int dx = tau % 3;
    const int wt0 = ((g * 9 + tau) * 2) * 1024;
    s16x8 ah[2], al[2], bh[2], bl[2];
#pragma unroll
    for (int fm = 0; fm < 2; ++fm) {
      ah[fm] = *reinterpret_cast<const s16x8*>(&WT[wt0 + (fm * 16 + mr) * 32 + kg]);
      al[fm] = *reinterpret_cast<const s16x8*>(&WT[wt0 + 1024 + (fm * 16 + mr) * 32 + kg]);
    }
#pragma unroll
    for (int fn = 0; fn < 2; ++fn) {
      const int slot = px0w + fn * 16 + mr + dx;   // 0..129
      const int sw = (slot & 7) * 8;
      bh[fn] = *reinterpret_cast<const s16x8*>(&xt[dy][slot][(kg) ^ sw]);
      bl[fn] = *reinterpret_cast<const s16x8*>(&xt[dy][slot][(32 + kg) ^ sw]);
    }
#pragma unroll
    for (int fm = 0; fm < 2; ++fm)
#pragma unroll
      for (int fn = 0; fn < 2; ++fn) {
        acc[fm][fn] = __builtin_amdgcn_mfma_f32_16x16x32_bf16(
            ah[fm], bh[fn], acc[fm][fn], 0, 0, 0);
        acc[fm][fn] = __builtin_amdgcn_mfma_f32_16x16x32_bf16(
            ah[fm], bl[fn], acc[fm][fn], 0, 0, 0);
        acc[fm][fn] = __builtin_amdgcn_mfma_f32_16x16x32_bf16(
            al[fm], bh[fn], acc[fm][fn], 0, 0, 0);
      }
  }

  const int mr4 = (lane >> 4) * 4;
  const float inv_s = 1.0f / sqrtf(1.0f + EPS_);
#pragma unroll
  for (int fm = 0; fm < 2; ++fm)
#pragma unroll
    for (int r = 0; r < 4; ++r) {
      const int c = g * 32 + fm * 16 + mr4 + r;
      const float scale = bng[c] * inv_s;
      const float cb = lb[c], sb = bnb[c];
#pragma unroll
      for (int fn = 0; fn < 2; ++fn) {
        const int px = px0w + fn * 16 + mr;
        const float val = fmaxf(fmaf(acc[fm][fn][r] + cb, scale, sb), 0.f);
        local_buf[(((size_t)(bb * C_ + c)) * H_ + y) * W_ + px] = val;
      }
    }
}

// ---------------------------------------------------------------------------
// K3 (per batch): window attention. 1 wave = 1 (window, head). lane = query.
// ---------------------------------------------------------------------------
__global__ __launch_bounds__(128) void k3_attn(
    const float* __restrict__ qkv_s, const float* __restrict__ rpb,
    float* __restrict__ attn_s) {
  __shared__ float kvs[2][2][64 * 32];
  __shared__ float rpb_s[225 * 8];
  const int tid = threadIdx.x;
  const int wid = tid >> 6, lane = tid & 63;
  const int pid = blockIdx.x * 2 + wid;
  const int win = pid >> 3, h = pid & 7;
  const int hh = win >> 4, ww = win & 15;

  for (int i = tid; i < 225 * 8; i += 128) rpb_s[i] = rpb[i];

  const size_t qbase = (((size_t)0 * NWIN_ + win) * NH_ + h) * 2048;
  const size_t kbase = (((size_t)1 * NWIN_ + win) * NH_ + h) * 2048;
  const size_t vbase = (((size_t)2 * NWIN_ + win) * NH_ + h) * 2048;

  float* Kl = kvs[wid][0];
  float* Vl = kvs[wid][1];
#pragma unroll
  for (int r = 0; r < 8; ++r) {
    const int e = r * 256 + lane * 4;
    *reinterpret_cast<float4*>(&Kl[e]) =
        *reinterpret_cast<const float4*>(&qkv_s[kbase + e]);
    *reinterpret_cast<float4*>(&Vl[e]) =
        *reinterpret_cast<const float4*>(&qkv_s[vbase + e]);
  }
  float4 qreg[8];
#pragma unroll
  for (int dd = 0; dd < 8; ++dd)
    qreg[dd] = *reinterpret_cast<const float4*>(&qkv_s[qbase + lane * 32 + dd * 4]);

  __syncthreads();

  float s[64];
#pragma unroll
  for (int j = 0; j < 64; ++j) {
    const float* kr = &Kl[j * 32];
    float sj = 0.f;
#pragma unroll
    for (int dd = 0; dd < 8; ++dd) {
      const float4 kv = *reinterpret_cast<const float4*>(&kr[dd * 4]);
      sj = fmaf(qreg[dd].x, kv.x, sj);
      sj = fmaf(qreg[dd].y, kv.y, sj);
      sj = fmaf(qreg[dd].z, kv.z, sj);
      sj = fmaf(qreg[dd].w, kv.w, sj);
    }
    s[j] = sj;
  }

  const float scale = 0.17677669529663687f;  // 32^-0.5
  const int r1 = lane >> 3, c1 = lane & 7;
  float m = -1e30f;
#pragma unroll
  for (int j = 0; j < 64; ++j) {
    const int jr = j >> 3, jc = j & 7;
    const int idx = (r1 - jr + 7) * 15 + (c1 - jc + 7);
    s[j] = fmaf(s[j], scale, rpb_s[idx * 8 + h]);
    m = fmaxf(m, s[j]);
  }
  float sum = 0.f;
#pragma unroll
  for (int j = 0; j < 64; ++j) {
    s[j] = __expf(s[j] - m);
    sum += s[j];
  }
  const float inv = 1.0f / sum;

  float o[32];
#pragma unroll
  for (int d = 0; d < 32; ++d) o[d] = 0.f;
#pragma unroll
  for (int j = 0; j < 64; ++j) {
    const float pj = s[j] * inv;
    const float* vr = &Vl[j * 32];
#pragma unroll
    for (int dd = 0; dd < 8; ++dd) {
      const float4 vv = *reinterpret_cast<const float4*>(&vr[dd * 4]);
      o[dd * 4 + 0] = fmaf(pj, vv.x, o[dd * 4 + 0]);
      o[dd * 4 + 1] = fmaf(pj, vv.y, o[dd * 4 + 1]);
      o[dd * 4 + 2] = fmaf(pj, vv.z, o[dd * 4 + 2]);
      o[dd * 4 + 3] = fmaf(pj, vv.w, o[dd * 4 + 3]);
    }
  }

  const int yy = hh * 8 + r1, xx = ww * 8 + c1;
  const size_t obase = ((size_t)(h * 32) * H_ + yy) * W_ + xx;
#pragma unroll
  for (int d = 0; d < 32; ++d) attn_s[obase + (size_t)d * HW_] = o[d];
}

// ---------------------------------------------------------------------------
// K4 (per batch): ax (8x1 pool, reflect-bottom) + ay (1x8, reflect-right)
//                 + local; writes pool IN-PLACE over local slice (same idx)
// ---------------------------------------------------------------------------
__global__ __launch_bounds__(256) void k4_pool(
    const float* __restrict__ attn_s, float* __restrict__ localpool) {
  const int bid = blockIdx.x;
  const int c = bid >> 6;
  const int rp = bid & 63;
  const int i = rp * 2 + (threadIdx.x >> 7);
  const int j = threadIdx.x & 127;
  const float* ap = attn_s + (size_t)c * HW_;
  float sx = 0.f;
#pragma unroll
  for (int dr = -3; dr <= 4; ++dr) {
    int r = i + dr;
    if (r < 0 || r > 128) continue;
    if (r == 128) r = 126;
    sx += ap[r * W_ + j];
  }
  float sy = 0.f;
#pragma unroll
  for (int dc = -3; dc <= 4; ++dc) {
    int cc = j + dc;
    if (cc < 0 || cc > 128) continue;
    if (cc == 128) cc = 126;
    sy += ap[i * W_ + cc];
  }
  const size_t idx = (size_t)c * HW_ + i * W_ + j;
  localpool[idx] = (sx + sy) * 0.125f + localpool[idx];
}

// ---------------------------------------------------------------------------
// K5 (per batch): depthwise 3x3 on reflect(0,1,0,1)-padded pool + bias + BN
// ---------------------------------------------------------------------------
__global__ __launch_bounds__(256) void k5_dw(
    const float* __restrict__ pool, const float* __restrict__ dww,
    const float* __restrict__ dwb, const float* __restrict__ bng,
    const float* __restrict__ bnb, float* __restrict__ dwout) {
  const int bid = blockIdx.x;
  const int c = bid >> 6;
  const int rp = bid & 63;
  const int i = rp * 2 + (threadIdx.x >> 7);
  const int j = threadIdx.x & 127;
  const float* pp = pool + (size_t)c * HW_;
  const float* wp = dww + c * 9;
  float acc = 0.f;
#pragma unroll
  for (int dy = 0; dy < 3; ++dy) {
    int r = i + dy - 1;
    if (r < 0) continue;
    if (r == 128) r = 126;
#pragma unroll
    for (int dx = 0; dx < 3; ++dx) {
      int cc = j + dx - 1;
      if (cc < 0) continue;
      if (cc == 128) cc = 126;
      acc = fmaf(wp[dy * 3 + dx], pp[r * W_ + cc], acc);
    }
  }
  const float scale = bng[c] / sqrtf(1.0f + EPS_);
  dwout[(size_t)c * HW_ + i * W_ + j] = fmaf(acc + dwb[c], scale, bnb[c]);
}

// ---------------------------------------------------------------------------
// K6 (per batch): pointwise 1x1 conv, split-bf16 MFMA. v2: 64-oc tiles ->
//   grid (128,4) = 512 blocks = 2/CU (was 256 = 1/CU, latency-starved).
//   4 waves as 2(m)x2(n): per wave 32oc x 64px, frags 2m x 4n.
// ---------------------------------------------------------------------------
__global__ __launch_bounds__(256) void k6_pw_mfma(
    const float* __restrict__ xin, const float* __restrict__ wq,
    const float* __restrict__ bias, float* __restrict__ outb) {
  __shared__ short s_a[2][64][40];
  __shared__ short s_b[2][128][40];
  const int tid = threadIdx.x;
  const int y   = blockIdx.x;
  const int oc0 = blockIdx.y * 64;

  const int lane = tid & 63;
  const int wid  = tid >> 6;
  const int m0w = (wid >> 1) * 32;   // 0 or 32
  const int n0w = (wid & 1) * 64;    // 0 or 64

  f32x4 acc[2][4];
#pragma unroll
  for (int i = 0; i < 2; ++i)
#pragma unroll
    for (int j = 0; j < 4; ++j) acc[i][j] = f32x4{0.f, 0.f, 0.f, 0.f};

  const int pcol = tid & 127;
  const int kq0  = tid >> 7;

  for (int k0 = 0; k0 < 256; k0 += 32) {
    // stage A: 64 oc x 32 k = 512 float4 -> 2 per thread
#pragma unroll
    for (int i = 0; i < 2; ++i) {
      const int ff = tid + i * 256;       // 0..511
      const int row = ff >> 3;            // 0..63
      const int c4 = ff & 7;
      const float4 w4 = *reinterpret_cast<const float4*>(
          &wq[(size_t)(oc0 + row) * 256 + k0 + c4 * 4]);
      short h0, h1, h2, h3, l0, l1, l2, l3;
      bf16_split(w4.x, h0, l0);
      bf16_split(w4.y, h1, l1);
      bf16_split(w4.z, h2, l2);
      bf16_split(w4.w, h3, l3);
      *reinterpret_cast<short4*>(&s_a[0][row][c4 * 4]) = make_short4(h0, h1, h2, h3);
      *reinterpret_cast<short4*>(&s_a[1][row][c4 * 4]) = make_short4(l0, l1, l2, l3);
    }
    // stage B (identical to k1)
#pragma unroll
    for (int it = 0; it < 4; ++it) {
      const int kq = kq0 * 4 + it;
      short h[4], l[4];
#pragma unroll
      for (int e = 0; e < 4; ++e) {
        const float v = xin[(size_t)(k0 + kq * 4 + e) * HW_ + y * W_ + pcol];
        bf16_split(v, h[e], l[e]);
      }
      *reinterpret_cast<short4*>(&s_b[0][pcol][kq * 4]) = make_short4(h[0], h[1], h[2], h[3]);
      *reinterpret_cast<short4*>(&s_b[1][pcol][kq * 4]) = make_short4(l[0], l[1], l[2], l[3]);
    }
    __syncthreads();

    const int mr = lane & 15;
    const int kg = (lane >> 4) * 8;
    s16x8 ah[2], al[2], bh[4], bl[4];
#pragma unroll
    for (int fm = 0; fm < 2; ++fm) {
      ah[fm] = *reinterpret_cast<const s16x8*>(&s_a[0][m0w + fm * 16 + mr][kg]);
      al[fm] = *reinterpret_cast<const s16x8*>(&s_a[1][m0w + fm * 16 + mr][kg]);
    }
#pragma unroll
    for (int fn = 0; fn < 4; ++fn) {
      bh[fn] = *reinterpret_cast<const s16x8*>(&s_b[0][n0w + fn * 16 + mr][kg]);
      bl[fn] = *reinterpret_cast<const s16x8*>(&s_b[1][n0w + fn * 16 + mr][kg]);
    }
#pragma unroll
    for (int fm = 0; fm < 2; ++fm)
#pragma unroll
      for (int fn = 0; fn < 4; ++fn) {
        acc[fm][fn] = __builtin_amdgcn_mfma_f32_16x16x32_bf16(
            ah[fm], bh[fn], acc[fm][fn], 0, 0, 0);
        acc[fm][fn] = __builtin_amdgcn_mfma_f32_16x16x32_bf16(
            ah[fm], bl[fn], acc[fm][fn], 0, 0, 0);
        acc[fm][fn] = __builtin_amdgcn_mfma_f32_16x16x32_bf16(
            al[fm], bh[fn], acc[fm][fn], 0, 0, 0);
      }
    __syncthreads();
  }

  const int mr4 = (lane >> 4) * 4;
  const int nn  = lane & 15;
#pragma unroll
  for (int fm = 0; fm < 2; ++fm) {
    const int ocb = oc0 + m0w + fm * 16 + mr4;
#pragma unroll
    for (int r = 0; r < 4; ++r) {
      const int oc = ocb + r;
      const float bo = bias[oc];
#pragma unroll
      for (int fn = 0; fn < 4; ++fn) {
        const int px = n0w + fn * 16 + nn;
        outb[(size_t)oc * HW_ + y * W_ + px] = acc[fm][fn][r] + bo;
      }
    }
  }
}

// ---------------------------------------------------------------------------
extern "C" void kernel_launch(void* const* d_in, const int* in_sizes, int n_in,
                              void* d_out, int out_size, void* d_ws, size_t ws_size,
                              hipStream_t stream) {
  const float* x          = (const float*)d_in[0];
  const float* qkv_w      = (const float*)d_in[1];
  const float* qkv_b      = (const float*)d_in[2];
  const float* local_w    = (const float*)d_in[3];
  const float* local_b    = (const float*)d_in[4];
  const float* local_bn_g = (const float*)d_in[5];
  const float* local_bn_b = (const float*)d_in[6];
  const float* rpb        = (const float*)d_in[7];
  const float* proj_dw_w  = (const float*)d_in[8];
  const float* proj_dw_b  = (const float*)d_in[9];
  const float* proj_bn_g  = (const float*)d_in[10];
  const float* proj_bn_b  = (const float*)d_in[11];
  const float* proj_pw_w  = (const float*)d_in[12];
  const float* proj_pw_b  = (const float*)d_in[13];
  float* out = (float*)d_out;
  float* ws = (float*)d_ws;

  const size_t CHW = (size_t)C_ * HW_;             // 4.19M floats / image
  const size_t NEED = 12 * CHW * 4;                // 201 MB (proven available)
  if (ws_size < NEED) return;

  float* local_all = ws;               // [8*CHW]  local -> pool (in-place)
  float* qkv_s     = ws + 8 * CHW;     // [3*CHW]  per-batch qkv
  float* attn_s    = qkv_s + 3 * CHW;  // [CHW]    attn -> dw (per batch)
  // WT (288 KB) lives at the start of qkv_s: consumed by k2 (before the batch
  // loop) and only then overwritten by k1 — in-order stream makes this safe.
  short* WT = (short*)qkv_s;

  k2_wt<<<dim3(288), 256, 0, stream>>>(local_w, WT);
  k2_mfma<<<dim3(8192), 256, 0, stream>>>(
      x, WT, local_b, local_bn_g, local_bn_b, local_all);

  for (int bb = 0; bb < 8; ++bb) {
    const float* xb = x + (size_t)bb * CHW;
    float* outb = out + (size_t)bb * CHW;
    float* local_s = local_all + (size_t)bb * CHW;
    k1_qkv_mfma<<<dim3(128, 6), 256, 0, stream>>>(xb, qkv_w, qkv_b, qkv_s);
    k3_attn<<<dim3(1024), 128, 0, stream>>>(qkv_s, rpb, attn_s);
    k4_pool<<<dim3(C_ * 64), 256, 0, stream>>>(attn_s, local_s);
    k5_dw<<<dim3(C_ * 64), 256, 0, stream>>>(local_s, proj_dw_w, proj_dw_b,
                                             proj_bn_g, proj_bn_b, attn_s);
    k6_pw_mfma<<<dim3(128, 4), 256, 0, stream>>>(attn_s, proj_pw_w, proj_pw_b, outb);
  }
}